// Round 2
// baseline (1085.899 us; speedup 1.0000x reference)
//
#include <hip/hip_runtime.h>
#include <math.h>

// Problem constants (from reference):
constexpr int Bc = 4, Tc = 512, Cc = 768, Hc = 12, HSc = 64;
constexpr int QKVN = 3 * Cc;  // 2304
constexpr double EPSd = 1e-6;

// ---------------------------------------------------------------------------
// qkv = x @ W_attn + b_attn, fp64 accumulate (decision-critical precision).
// Register-tiled: block 256, tile = 16 rows x 768 cols, thread = 16x3 accs.
// x rows staged in LDS (broadcast reads, conflict-free); W streamed coalesced.
// ---------------------------------------------------------------------------
__global__ void __launch_bounds__(256) gemm_qkv_f64(
    const float* __restrict__ X, const float* __restrict__ W,
    const float* __restrict__ bias, float* __restrict__ outp) {
  __shared__ float xs[16][Cc];
  const int tx = threadIdx.x;
  const int r0 = blockIdx.x * 16;
  const int o0 = blockIdx.y * 768 + tx;  // +0, +256, +512
  for (int r = 0; r < 16; ++r)
    for (int c = tx; c < Cc; c += 256)
      xs[r][c] = X[(size_t)(r0 + r) * Cc + c];
  __syncthreads();
  double acc0[16], acc1[16], acc2[16];
  const double b0 = (double)bias[o0];
  const double b1 = (double)bias[o0 + 256];
  const double b2 = (double)bias[o0 + 512];
#pragma unroll
  for (int r = 0; r < 16; ++r) { acc0[r] = b0; acc1[r] = b1; acc2[r] = b2; }
#pragma unroll 2
  for (int c = 0; c < Cc; ++c) {
    const size_t wrow = (size_t)c * QKVN + o0;
    const double w0 = (double)W[wrow];
    const double w1 = (double)W[wrow + 256];
    const double w2 = (double)W[wrow + 512];
#pragma unroll
    for (int r = 0; r < 16; ++r) {
      const double xv = (double)xs[r][c];
      acc0[r] += xv * w0;
      acc1[r] += xv * w1;
      acc2[r] += xv * w2;
    }
  }
#pragma unroll
  for (int r = 0; r < 16; ++r) {
    const size_t orow = (size_t)(r0 + r) * QKVN + o0;
    outp[orow]       = (float)acc0[r];
    outp[orow + 256] = (float)acc1[r];
    outp[orow + 512] = (float)acc2[r];
  }
}

// ---------------------------------------------------------------------------
// S[bh][i][j] = q_i . k_j (fp64 acc, fp32 store), -inf where j > i.
// Tiled 64x64 per block; upper tiles fill -inf only. Pads break LDS conflicts.
// ---------------------------------------------------------------------------
__global__ void __launch_bounds__(256) sims_kernel(
    const float* __restrict__ qkv, float* __restrict__ S) {
  const int jt = blockIdx.x, it = blockIdx.y, bh = blockIdx.z;
  const int b = bh / Hc, h = bh % Hc;
  const int tx = threadIdx.x;
  const int j = tx & 63, iq = tx >> 6;
  float* Shead = S + (size_t)bh * Tc * Tc;
  if (jt > it) {
#pragma unroll
    for (int r = 0; r < 16; ++r) {
      const int i = it * 64 + iq * 16 + r;
      Shead[(size_t)i * Tc + jt * 64 + j] = -INFINITY;
    }
    return;
  }
  __shared__ float qs[64][65], ks[64][65];
  const float* base = qkv + (size_t)b * Tc * QKVN + h * HSc;
  for (int idx = tx; idx < 4096; idx += 256) {
    const int r = idx >> 6, d = idx & 63;
    qs[r][d] = base[(size_t)(it * 64 + r) * QKVN + d];
    ks[r][d] = base[(size_t)(jt * 64 + r) * QKVN + Cc + d];
  }
  __syncthreads();
  double acc[16];
#pragma unroll
  for (int r = 0; r < 16; ++r) acc[r] = 0.0;
  for (int d = 0; d < HSc; ++d) {
    const double kv = (double)ks[j][d];
#pragma unroll
    for (int r = 0; r < 16; ++r)
      acc[r] += (double)qs[iq * 16 + r][d] * kv;
  }
#pragma unroll
  for (int r = 0; r < 16; ++r) {
    const int i = it * 64 + iq * 16 + r;
    const int jj = jt * 64 + j;
    Shead[(size_t)i * Tc + jj] = (jj <= i) ? (float)acc[r] : -INFINITY;
  }
}

// ---------------------------------------------------------------------------
// Greedy DPP selection: one wave per (b,h,t). sims read from precomputed S;
// candidate k-rows gathered coalesced into LDS; LU numerics identical to the
// passing Round-1 kernel (fp64 partial-pivot LU = LAPACK dgetf2 order).
// ---------------------------------------------------------------------------
__global__ void __launch_bounds__(64) select_kernel(
    const float* __restrict__ qkv, const float* __restrict__ S,
    float* __restrict__ y) {
  const int bid = blockIdx.x;  // bh*T + i
  const int i = bid % Tc;
  const int bh = bid / Tc;
  const int b = bh / Hc;
  const int h = bh % Hc;
  const int lane = threadIdx.x;

  const float* base = qkv + (size_t)b * Tc * QKVN + h * HSc;
  const float* kbase = base + Cc;
  const float* vbase = base + 2 * Cc;
  const float* Srow = S + ((size_t)bh * Tc + i) * Tc;

  __shared__ float Kc[17][65];       // rows 0..15: candidates, row 16: k_i
  __shared__ double g0[8][8];        // gram of selected set
  __shared__ double crossm[16][9];   // cross[m][a] = k_cand[m] . k_sel[a]
  __shared__ double Amat[16][65];    // per-candidate LU scratch (stride-65 pad)
  __shared__ double cnorm[16];
  __shared__ int topidxS[16];
  __shared__ int selS[8];

  // ---- sims from precomputed S row (coalesced, -inf already applied) ----
  double sim[8];
#pragma unroll
  for (int jj = 0; jj < 8; ++jj)
    sim[jj] = (double)Srow[jj * 64 + lane];

  // ---- top-16, descending, ties -> lower index (jax.lax.top_k semantics) ----
  unsigned taken = 0;  // per-lane bitmask over jj
  unsigned avail = 0;  // uniform 16-bit candidate availability
  for (int m = 0; m < 16; ++m) {
    double bv = -INFINITY;
    int bj = Tc;  // sentinel larger than any index
#pragma unroll
    for (int jj = 0; jj < 8; ++jj) {
      const int j = jj * 64 + lane;
      if (!((taken >> jj) & 1u)) {
        const double val = sim[jj];
        if (val > bv || (val == bv && j < bj)) { bv = val; bj = j; }
      }
    }
#pragma unroll
    for (int off = 32; off >= 1; off >>= 1) {
      const double ov = __shfl_down(bv, off);
      const int oj = __shfl_down(bj, off);
      if (ov > bv || (ov == bv && oj < bj)) { bv = ov; bj = oj; }
    }
    bv = __shfl(bv, 0);
    bj = __shfl(bj, 0);
    if (lane == 0) topidxS[m] = bj;
    if ((bj & 63) == lane) taken |= (1u << (bj >> 6));
    if (bv > -INFINITY && bj != i) avail |= (1u << m);
  }
  __syncthreads();

  // ---- gather candidate k-rows + k_i into LDS (coalesced) ----
#pragma unroll
  for (int m = 0; m < 16; ++m)
    Kc[m][lane] = kbase[(size_t)topidxS[m] * QKVN + lane];
  Kc[16][lane] = kbase[(size_t)i * QKVN + lane];
  __syncthreads();

  // ---- cnorm[m], cross[m][0] wave-parallel: 4 lanes per candidate ----
  const int mq = lane >> 2;  // candidate 0..15
  const int qq = lane & 3;   // quarter 0..3
  {
    double nrm = 0.0, c0 = 0.0;
#pragma unroll
    for (int dd = 0; dd < 16; ++dd) {
      const int d = qq * 16 + dd;
      const double kv = (double)Kc[mq][d];
      nrm += kv * kv;
      c0 += kv * (double)Kc[16][d];
    }
    nrm += __shfl_xor(nrm, 1); nrm += __shfl_xor(nrm, 2);
    c0 += __shfl_xor(c0, 1);   c0 += __shfl_xor(c0, 2);
    if (qq == 0) { cnorm[mq] = nrm; crossm[mq][0] = c0; }
  }

  // ---- k_i . k_i (tree reduce, identical to Round-1) ----
  double kii;
  {
    const double t = (double)Kc[16][lane];
    double sq = t * t;
#pragma unroll
    for (int off = 32; off >= 1; off >>= 1) sq += __shfl_down(sq, off);
    kii = __shfl(sq, 0);
  }
  if (lane == 0) { g0[0][0] = kii; selS[0] = i; }
  double cur_s = -log(kii + EPSd);
  int count = 1;
  __syncthreads();

  // ---- greedy loop: up to 7 additions ----
  for (int it = 0; it < 7; ++it) {
    double sorig = -INFINITY;
    if (lane < 16 && ((avail >> lane) & 1u)) {
      const int n = count + 1;
      double* A = Amat[lane];
      for (int a = 0; a < count; ++a) {
        for (int bb = 0; bb < count; ++bb) A[a * 8 + bb] = g0[a][bb];
        const double cv = crossm[lane][a];
        A[count * 8 + a] = cv;
        A[a * 8 + count] = cv;
      }
      A[count * 8 + count] = cnorm[lane];
      // LAPACK-style LU with partial pivoting (first max, reciprocal scaling)
      double det = 1.0;
      for (int p = 0; p < n; ++p) {
        int piv = p;
        double mx = fabs(A[p * 8 + p]);
        for (int r = p + 1; r < n; ++r) {
          const double ar = fabs(A[r * 8 + p]);
          if (ar > mx) { mx = ar; piv = r; }
        }
        if (piv != p) {
          for (int c = 0; c < n; ++c) {
            const double t2 = A[p * 8 + c];
            A[p * 8 + c] = A[piv * 8 + c];
            A[piv * 8 + c] = t2;
          }
          det = -det;
        }
        const double dpp = A[p * 8 + p];
        det *= dpp;
        if (dpp != 0.0) {
          const double inv = 1.0 / dpp;
          for (int r = p + 1; r < n; ++r) {
            const double f = A[r * 8 + p] * inv;
            for (int c = p + 1; c < n; ++c) A[r * 8 + c] -= f * A[p * 8 + c];
          }
        }
      }
      sorig = -log(det + EPSd) / (double)n;
    }
    // argmax over candidates; NaN acts as max (numpy argmax), ties -> lower m
    double bkey = (lane < 16) ? (__builtin_isnan(sorig) ? INFINITY : sorig)
                              : -INFINITY;
    int bm = lane;
#pragma unroll
    for (int off = 32; off >= 1; off >>= 1) {
      const double ok2 = __shfl_down(bkey, off);
      const int om = __shfl_down(bm, off);
      if (ok2 > bkey || (ok2 == bkey && om < bm)) { bkey = ok2; bm = om; }
    }
    bm = __shfl(bm, 0);
    const double best_s = __shfl(sorig, bm);  // original (possibly NaN) value
    const bool accept = (avail != 0u) && ((best_s > cur_s) || (count < 2));
    if (!accept) break;  // uniform across the wave
    const int bestIdx = topidxS[bm];
    __syncthreads();
    if (lane < count) {
      const double cv = crossm[bm][lane];
      g0[count][lane] = cv;
      g0[lane][count] = cv;
    }
    if (lane == 0) {
      g0[count][count] = cnorm[bm];
      selS[count] = bestIdx;
    }
    // crossm[:, count] = Kc[:] . Kc[bm], wave-parallel from LDS
    {
      double cp = 0.0;
#pragma unroll
      for (int dd = 0; dd < 16; ++dd) {
        const int d = qq * 16 + dd;
        cp += (double)Kc[mq][d] * (double)Kc[bm][d];
      }
      cp += __shfl_xor(cp, 1); cp += __shfl_xor(cp, 2);
      if (qq == 0) crossm[mq][count] = cp;
    }
    avail &= ~(1u << bm);
    cur_s = best_s;
    ++count;
    __syncthreads();
  }
  __syncthreads();

  // ---- output: mean of selected v rows; y layout [B,T,H,HS] = [B,T,C] ----
  double acc = 0.0;
  for (int a = 0; a < count; ++a)
    acc += (double)vbase[(size_t)selS[a] * QKVN + lane];
  y[(((size_t)b * Tc + i) * Hc + h) * HSc + lane] = (float)(acc / (double)count);
}

// ---------------------------------------------------------------------------
// out = y @ W_proj + b_proj, fp32 (output-only path; error ~1e-5 << threshold)
// ---------------------------------------------------------------------------
__global__ void __launch_bounds__(256) gemm_proj_f32(
    const float* __restrict__ X, const float* __restrict__ W,
    const float* __restrict__ bias, float* __restrict__ outp) {
  __shared__ float xs[4][Cc];
  const int tx = threadIdx.x;
  const int r0 = blockIdx.x * 4;
  for (int r = 0; r < 4; ++r)
    for (int c = tx; c < Cc; c += 256)
      xs[r][c] = X[(size_t)(r0 + r) * Cc + c];
  __syncthreads();
  float acc0[4], acc1[4], acc2[4];
  const float b0 = bias[tx], b1 = bias[tx + 256], b2 = bias[tx + 512];
#pragma unroll
  for (int r = 0; r < 4; ++r) { acc0[r] = b0; acc1[r] = b1; acc2[r] = b2; }
#pragma unroll 4
  for (int c = 0; c < Cc; ++c) {
    const size_t wrow = (size_t)c * Cc + tx;
    const float w0 = W[wrow];
    const float w1 = W[wrow + 256];
    const float w2 = W[wrow + 512];
#pragma unroll
    for (int r = 0; r < 4; ++r) {
      const float xv = xs[r][c];
      acc0[r] += xv * w0;
      acc1[r] += xv * w1;
      acc2[r] += xv * w2;
    }
  }
#pragma unroll
  for (int r = 0; r < 4; ++r) {
    const size_t orow = (size_t)(r0 + r) * Cc + tx;
    outp[orow]       = acc0[r];
    outp[orow + 256] = acc1[r];
    outp[orow + 512] = acc2[r];
  }
}

// ---------------------------------------------------------------------------
extern "C" void kernel_launch(void* const* d_in, const int* in_sizes, int n_in,
                              void* d_out, int out_size, void* d_ws, size_t ws_size,
                              hipStream_t stream) {
  (void)in_sizes; (void)n_in; (void)out_size; (void)ws_size;
  const float* x  = (const float*)d_in[0];
  const float* Wa = (const float*)d_in[1];
  const float* ba = (const float*)d_in[2];
  const float* Wp = (const float*)d_in[3];
  const float* bp = (const float*)d_in[4];
  float* out = (float*)d_out;

  float* qkv = (float*)d_ws;                          // [B*T][2304] fp32, 18.9MB
  float* y   = qkv + (size_t)Bc * Tc * QKVN;          // [B*T][768]  fp32,  6.3MB
  float* S   = y + (size_t)Bc * Tc * Cc;              // [48][512][512],   50.3MB

  // 1) qkv = x @ W_attn + b_attn  (fp64 accumulate)
  hipLaunchKernelGGL(gemm_qkv_f64, dim3((Bc * Tc) / 16, 3), dim3(256), 0,
                     stream, x, Wa, ba, qkv);
  // 2) S = Q K^T per head, causal -inf (fp64 accumulate, fp32 store)
  hipLaunchKernelGGL(sims_kernel, dim3(8, 8, Bc * Hc), dim3(256), 0,
                     stream, qkv, S);
  // 3) greedy DPP per (b,h,t); writes y [B,T,C]
  hipLaunchKernelGGL(select_kernel, dim3(Bc * Hc * Tc), dim3(64), 0,
                     stream, qkv, S, y);
  // 4) out = y @ W_proj + b_proj (fp32)
  hipLaunchKernelGGL(gemm_proj_f32, dim3((Bc * Tc) / 4, 1), dim3(256), 0,
                     stream, y, Wp, bp, out);
}

// Round 3
// 726.985 us; speedup vs baseline: 1.4937x; 1.4937x over previous
//
#include <hip/hip_runtime.h>
#include <math.h>

// Problem constants (from reference):
constexpr int Bc = 4, Tc = 512, Cc = 768, Hc = 12, HSc = 64;
constexpr int QKVN = 3 * Cc;  // 2304
constexpr double EPSd = 1e-6;

// ---------------------------------------------------------------------------
// q,k = x @ W_attn[:, :1536] + b_attn[:1536], fp64 accumulate (decision-
// critical). 8 rows x 3 cols per thread = 24 f64 accs (48 VGPRs — no spill;
// launch_bounds(256,1) so the allocator doesn't cap VGPRs and spill like R2).
// ---------------------------------------------------------------------------
__global__ void __launch_bounds__(256, 1) gemm_qk_f64(
    const float* __restrict__ X, const float* __restrict__ W,
    const float* __restrict__ bias, float* __restrict__ outp) {
  __shared__ float xs[8][Cc];
  const int tx = threadIdx.x;
  const int r0 = blockIdx.x * 8;
  const int o0 = blockIdx.y * 768 + tx;  // blockIdx.y in {0,1} -> cols 0..1535
  for (int idx = tx; idx < 8 * Cc; idx += 256) {
    const int r = idx / Cc, c = idx % Cc;
    xs[r][c] = X[(size_t)(r0 + r) * Cc + c];
  }
  __syncthreads();
  double acc0[8], acc1[8], acc2[8];
  const double b0 = (double)bias[o0];
  const double b1 = (double)bias[o0 + 256];
  const double b2 = (double)bias[o0 + 512];
#pragma unroll
  for (int r = 0; r < 8; ++r) { acc0[r] = b0; acc1[r] = b1; acc2[r] = b2; }
#pragma unroll 4
  for (int c = 0; c < Cc; ++c) {
    const size_t wrow = (size_t)c * QKVN + o0;
    const double w0 = (double)W[wrow];
    const double w1 = (double)W[wrow + 256];
    const double w2 = (double)W[wrow + 512];
#pragma unroll
    for (int r = 0; r < 8; ++r) {
      const double xv = (double)xs[r][c];
      acc0[r] += xv * w0;
      acc1[r] += xv * w1;
      acc2[r] += xv * w2;
    }
  }
#pragma unroll
  for (int r = 0; r < 8; ++r) {
    const size_t orow = (size_t)(r0 + r) * QKVN + o0;
    outp[orow]       = (float)acc0[r];
    outp[orow + 256] = (float)acc1[r];
    outp[orow + 512] = (float)acc2[r];
  }
}

// ---------------------------------------------------------------------------
// Generic fp32 GEMM (K=768): used for v-columns of qkv (tolerance is loose —
// v only feeds the averaged output) and for the final projection.
// 4 rows x 3 cols per thread.
// ---------------------------------------------------------------------------
__global__ void __launch_bounds__(256) gemm_f32_k768(
    const float* __restrict__ X, const float* __restrict__ W,
    const float* __restrict__ bias, float* __restrict__ outp,
    int ldW, int colOff, int ldOut) {
  __shared__ float xs[4][Cc];
  const int tx = threadIdx.x;
  const int r0 = blockIdx.x * 4;
  const int o0 = colOff + tx;
  for (int r = 0; r < 4; ++r)
    for (int c = tx; c < Cc; c += 256)
      xs[r][c] = X[(size_t)(r0 + r) * Cc + c];
  __syncthreads();
  float acc0[4], acc1[4], acc2[4];
  const float b0 = bias[o0], b1 = bias[o0 + 256], b2 = bias[o0 + 512];
#pragma unroll
  for (int r = 0; r < 4; ++r) { acc0[r] = b0; acc1[r] = b1; acc2[r] = b2; }
#pragma unroll 4
  for (int c = 0; c < Cc; ++c) {
    const size_t wrow = (size_t)c * ldW + o0;
    const float w0 = W[wrow];
    const float w1 = W[wrow + 256];
    const float w2 = W[wrow + 512];
#pragma unroll
    for (int r = 0; r < 4; ++r) {
      const float xv = xs[r][c];
      acc0[r] += xv * w0;
      acc1[r] += xv * w1;
      acc2[r] += xv * w2;
    }
  }
#pragma unroll
  for (int r = 0; r < 4; ++r) {
    const size_t orow = (size_t)(r0 + r) * ldOut + o0;
    outp[orow]       = acc0[r];
    outp[orow + 256] = acc1[r];
    outp[orow + 512] = acc2[r];
  }
}

// ---------------------------------------------------------------------------
// S[bh][i][j] = q_i . k_j (fp64 acc, fp32 store), -inf where j > i. (as R2)
// ---------------------------------------------------------------------------
__global__ void __launch_bounds__(256) sims_kernel(
    const float* __restrict__ qkv, float* __restrict__ S) {
  const int jt = blockIdx.x, it = blockIdx.y, bh = blockIdx.z;
  const int b = bh / Hc, h = bh % Hc;
  const int tx = threadIdx.x;
  const int j = tx & 63, iq = tx >> 6;
  float* Shead = S + (size_t)bh * Tc * Tc;
  if (jt > it) {
#pragma unroll
    for (int r = 0; r < 16; ++r) {
      const int i = it * 64 + iq * 16 + r;
      Shead[(size_t)i * Tc + jt * 64 + j] = -INFINITY;
    }
    return;
  }
  __shared__ float qs[64][65], ks[64][65];
  const float* base = qkv + (size_t)b * Tc * QKVN + h * HSc;
  for (int idx = tx; idx < 4096; idx += 256) {
    const int r = idx >> 6, d = idx & 63;
    qs[r][d] = base[(size_t)(it * 64 + r) * QKVN + d];
    ks[r][d] = base[(size_t)(jt * 64 + r) * QKVN + Cc + d];
  }
  __syncthreads();
  double acc[16];
#pragma unroll
  for (int r = 0; r < 16; ++r) acc[r] = 0.0;
  for (int d = 0; d < HSc; ++d) {
    const double kv = (double)ks[j][d];
#pragma unroll
    for (int r = 0; r < 16; ++r)
      acc[r] += (double)qs[iq * 16 + r][d] * kv;
  }
#pragma unroll
  for (int r = 0; r < 16; ++r) {
    const int i = it * 64 + iq * 16 + r;
    const int jj = jt * 64 + j;
    Shead[(size_t)i * Tc + jj] = (jj <= i) ? (float)acc[r] : -INFINITY;
  }
}

// ---------------------------------------------------------------------------
// Greedy DPP selection, 4 tokens per wave (4 groups x 16 lanes; tokens share
// (b,h)). Per candidate: identity-padded 8x8 gram, register-resident fully
// unrolled partial-pivot LU — bit-identical to the reference's det on the
// padded 8x8 (identity rows pass through LU exactly: zero column entries
// never win pivots; f=0 updates are exact no-ops).
// ---------------------------------------------------------------------------
__global__ void __launch_bounds__(64, 2) select4_kernel(
    const float* __restrict__ qkv, const float* __restrict__ S,
    float* __restrict__ y) {
  const int bid = blockIdx.x;          // 4 tokens per block
  const int bh = bid >> 7;             // 128 blocks per (b,h)
  const int i0 = (bid & 127) << 2;
  const int b = bh / Hc;
  const int h = bh % Hc;
  const int lane = threadIdx.x;
  const int g = lane >> 4;             // token group 0..3
  const int l16 = lane & 15;
  const int i_g = i0 + g;

  const float* base = qkv + (size_t)b * Tc * QKVN + h * HSc;
  const float* kbase = base + Cc;
  const float* vbase = base + 2 * Cc;

  __shared__ float Kc[4][17][68];      // cands 0..15 + k_i at 16; pad 68 (banks)
  __shared__ double g0S[4][8][8];      // gram of selected set (zero-padded)
  __shared__ double crossm[4][16][10]; // cross[g][m][a]; stride 10 -> 16B align
  __shared__ double cnormS[4][16];
  __shared__ int topidxS[4][16];
  __shared__ int selS[4][8];

  // zero g0S (its zero-padding is semantically load-bearing)
  {
    double* gz = (double*)g0S;
#pragma unroll
    for (int t = 0; t < 4; ++t) gz[lane + 64 * t] = 0.0;
  }

  // ---- phase 1: load sims row; build sortable u64 keys ----
  // key = (sortable(float) << 32) | (511 - j): max key == max val, tie -> low j
  const float* Srow = S + ((size_t)bh * Tc + i_g) * Tc;
  const float4* Sq = reinterpret_cast<const float4*>(Srow);
  unsigned long long key[32];
#pragma unroll
  for (int r4 = 0; r4 < 8; ++r4) {
    const float4 v4 = Sq[l16 * 8 + r4];
    const float vv[4] = {v4.x, v4.y, v4.z, v4.w};
#pragma unroll
    for (int c = 0; c < 4; ++c) {
      const int j = l16 * 32 + r4 * 4 + c;
      const unsigned u = __float_as_uint(vv[c]);
      const unsigned s = (u & 0x80000000u) ? ~u : (u | 0x80000000u);
      key[r4 * 4 + c] = ((unsigned long long)s << 32) | (unsigned)(511 - j);
    }
  }

  // ---- phase 2: top-16 per group (exact jax.lax.top_k semantics) ----
  unsigned avail = 0;
  for (int m = 0; m < 16; ++m) {
    unsigned long long bk = 0;
#pragma unroll
    for (int r = 0; r < 32; ++r) bk = (key[r] > bk) ? key[r] : bk;
#pragma unroll
    for (int msk = 1; msk <= 8; msk <<= 1) {
      const unsigned long long ok = __shfl_xor(bk, msk);
      bk = (ok > bk) ? ok : bk;
    }
    const int j = 511 - (int)(unsigned)(bk & 0xFFFFFFFFull);
    const unsigned shi = (unsigned)(bk >> 32);
    if (l16 == 0) topidxS[g][m] = j;
    if (shi > 0x007FFFFFu && j != i_g) avail |= (1u << m);  // finite && != i
#pragma unroll
    for (int r = 0; r < 32; ++r) key[r] = (key[r] == bk) ? 0ull : key[r];
  }
  __syncthreads();

  // ---- phase 3: gather candidate k-rows + k_i into LDS (coalesced) ----
#pragma unroll
  for (int g2 = 0; g2 < 4; ++g2)
    for (int m2 = 0; m2 < 17; ++m2) {
      const int j = (m2 < 16) ? topidxS[g2][m2] : (i0 + g2);
      Kc[g2][m2][lane] = kbase[(size_t)j * QKVN + lane];
    }
  __syncthreads();

  // ---- phase 4: cnorm, cross[.][0], kii (per-lane f64 dots from LDS) ----
  const float4* myrow = reinterpret_cast<const float4*>(&Kc[g][l16][0]);
  const float4* irow  = reinterpret_cast<const float4*>(&Kc[g][16][0]);
  double kii;
  {
    double nrm = 0.0, c0 = 0.0, ki2 = 0.0;
#pragma unroll
    for (int q = 0; q < 16; ++q) {
      const float4 a4 = myrow[q];
      const float4 i4 = irow[q];
      nrm += (double)a4.x * a4.x; nrm += (double)a4.y * a4.y;
      nrm += (double)a4.z * a4.z; nrm += (double)a4.w * a4.w;
      c0  += (double)a4.x * i4.x; c0  += (double)a4.y * i4.y;
      c0  += (double)a4.z * i4.z; c0  += (double)a4.w * i4.w;
      ki2 += (double)i4.x * i4.x; ki2 += (double)i4.y * i4.y;
      ki2 += (double)i4.z * i4.z; ki2 += (double)i4.w * i4.w;
    }
    cnormS[g][l16] = nrm;
    crossm[g][l16][0] = c0;
#pragma unroll
    for (int t = 1; t < 10; ++t) crossm[g][l16][t] = 0.0;
    kii = ki2;
  }
  if (l16 == 0) { g0S[g][0][0] = kii; selS[g][0] = i_g; }
  double cur_s = -log(kii + EPSd);
  int count = 1;
  bool done = false;
  __syncthreads();

  // ---- phase 5: greedy loop, 7 fixed iterations (reference scan shape) ----
  const double cnorm_l = cnormS[g][l16];
  for (int it = 0; it < 7; ++it) {
    if (__ballot(done) == ~0ull) break;  // wave-uniform early out
    // per-lane border values
    double cr[8];
#pragma unroll
    for (int t = 0; t < 8; ++t) cr[t] = crossm[g][l16][t];
    // build identity-padded 8x8 (exactly the reference's `grams` matrix)
    double A[8][8];
#pragma unroll
    for (int a = 0; a < 8; ++a)
#pragma unroll
      for (int bb = 0; bb < 8; ++bb) {
        double v = g0S[g][a][bb];
        v = (a == bb && a > count) ? 1.0 : v;
        v = (a == count) ? cr[bb] : v;
        v = (bb == count) ? ((a == count) ? cnorm_l : cr[a]) : v;
        A[a][bb] = v;
      }
    // fully unrolled partial-pivot LU (LAPACK dgetf2 order, as R1/R2)
    double det = 1.0;
#pragma unroll
    for (int p = 0; p < 8; ++p) {
      int piv = p;
      double mx = fabs(A[p][p]);
#pragma unroll
      for (int r = p + 1; r < 8; ++r) {
        const double ar = fabs(A[r][p]);
        const bool cgt = ar > mx;
        mx = cgt ? ar : mx;
        piv = cgt ? r : piv;
      }
#pragma unroll
      for (int r = p + 1; r < 8; ++r) {
        const bool dos = (piv == r);
#pragma unroll
        for (int c2 = p; c2 < 8; ++c2) {
          const double t2 = A[p][c2];
          A[p][c2] = dos ? A[r][c2] : A[p][c2];
          A[r][c2] = dos ? t2 : A[r][c2];
        }
      }
      det = (piv != p) ? -det : det;
      const double dpp = A[p][p];
      det *= dpp;
      const double inv = (dpp != 0.0) ? 1.0 / dpp : 0.0;
#pragma unroll
      for (int r = p + 1; r < 8; ++r) {
        const double f = A[r][p] * inv;
#pragma unroll
        for (int c2 = p + 1; c2 < 8; ++c2) A[r][c2] -= f * A[p][c2];
      }
    }
    const bool act = !done && ((avail >> l16) & 1u);
    const double val = -log(det + EPSd) / (double)(count + 1);
    const double sorig = act ? val : -INFINITY;
    // group argmax; NaN acts as max (numpy argmax), ties -> lower m
    double bkey = __builtin_isnan(sorig) ? INFINITY : sorig;
    int bm = l16;
#pragma unroll
    for (int msk = 1; msk <= 8; msk <<= 1) {
      const double ok2 = __shfl_xor(bkey, msk);
      const int om = __shfl_xor(bm, msk);
      const bool t2 = (ok2 > bkey) || (ok2 == bkey && om < bm);
      bkey = t2 ? ok2 : bkey;
      bm = t2 ? om : bm;
    }
    const double best_s = __shfl(sorig, (g << 4) | bm);
    const bool X = (avail != 0u) && ((best_s > cur_s) || (count < 2));
    const bool accept = (!done) && X;
    __syncthreads();
    if (accept) {
      if (l16 < count) {
        const double cv = crossm[g][bm][l16];
        g0S[g][count][l16] = cv;
        g0S[g][l16][count] = cv;
      }
      if (l16 == 0) {
        g0S[g][count][count] = cnormS[g][bm];
        selS[g][count] = topidxS[g][bm];
      }
      // crossm[.][count] = Kc[.] . Kc[bm]
      const float4* brow = reinterpret_cast<const float4*>(&Kc[g][bm][0]);
      double cp = 0.0;
#pragma unroll
      for (int q = 0; q < 16; ++q) {
        const float4 a4 = myrow[q];
        const float4 b4 = brow[q];
        cp += (double)a4.x * b4.x; cp += (double)a4.y * b4.y;
        cp += (double)a4.z * b4.z; cp += (double)a4.w * b4.w;
      }
      crossm[g][l16][count] = cp;
    }
    __syncthreads();
    if (accept) {
      avail &= ~(1u << bm);
      cur_s = best_s;
      ++count;
    }
    done = done || !X;
  }
  __syncthreads();

  // ---- phase 6: output = mean of selected v rows; y is [B,T,H,HS] ----
#pragma unroll
  for (int g2 = 0; g2 < 4; ++g2) {
    const int cnt = __shfl(count, g2 << 4);
    double acc = 0.0;
#pragma unroll
    for (int a = 0; a < 8; ++a)
      if (a < cnt) acc += (double)vbase[(size_t)selS[g2][a] * QKVN + lane];
    y[(((size_t)b * Tc + (i0 + g2)) * Hc + h) * HSc + lane] =
        (float)(acc / (double)cnt);
  }
}

// ---------------------------------------------------------------------------
extern "C" void kernel_launch(void* const* d_in, const int* in_sizes, int n_in,
                              void* d_out, int out_size, void* d_ws, size_t ws_size,
                              hipStream_t stream) {
  (void)in_sizes; (void)n_in; (void)out_size; (void)ws_size;
  const float* x  = (const float*)d_in[0];
  const float* Wa = (const float*)d_in[1];
  const float* ba = (const float*)d_in[2];
  const float* Wp = (const float*)d_in[3];
  const float* bp = (const float*)d_in[4];
  float* out = (float*)d_out;

  float* qkv = (float*)d_ws;                          // [B*T][2304] fp32, 18.9MB
  float* y   = qkv + (size_t)Bc * Tc * QKVN;          // [B*T][768]  fp32,  6.3MB
  float* S   = y + (size_t)Bc * Tc * Cc;              // [48][512][512],   50.3MB

  // 1a) q,k cols (fp64 accumulate) ; 1b) v cols (fp32)
  hipLaunchKernelGGL(gemm_qk_f64, dim3((Bc * Tc) / 8, 2), dim3(256), 0,
                     stream, x, Wa, ba, qkv);
  hipLaunchKernelGGL(gemm_f32_k768, dim3((Bc * Tc) / 4, 1), dim3(256), 0,
                     stream, x, Wa, ba, qkv, QKVN, 2 * Cc, QKVN);
  // 2) S = Q K^T per head, causal -inf
  hipLaunchKernelGGL(sims_kernel, dim3(8, 8, Bc * Hc), dim3(256), 0,
                     stream, qkv, S);
  // 3) greedy DPP, 4 tokens/wave
  hipLaunchKernelGGL(select4_kernel, dim3(Bc * Hc * Tc / 4), dim3(64), 0,
                     stream, qkv, S, y);
  // 4) out = y @ W_proj + b_proj (fp32)
  hipLaunchKernelGGL(gemm_f32_k768, dim3((Bc * Tc) / 4, 1), dim3(256), 0,
                     stream, y, Wp, bp, out, Cc, 0, Cc);
}

// Round 4
// 500.551 us; speedup vs baseline: 2.1694x; 1.4524x over previous
//
#include <hip/hip_runtime.h>
#include <math.h>

// Problem constants (from reference):
constexpr int Bc = 4, Tc = 512, Cc = 768, Hc = 12, HSc = 64;
constexpr int QKVN = 3 * Cc;  // 2304
constexpr double EPSd = 1e-6;

// ---------------------------------------------------------------------------
// out[r0:r0+ROWS, colGrp*768 + {0,256,512} + tx] = X @ W + bias, fp32.
// fp32 is safe: numpy's own sgemm q,k differ from correctly-rounded fp32 by
// ~1e-6 rel and we pass -> decision cascade robust to this class.
// x-tile stored TRANSPOSED in LDS: xs[c][r] -> per k-step the ROWS values are
// contiguous -> ROWS/4 wave-uniform ds_read_b128 broadcasts.
// ---------------------------------------------------------------------------
template <int ROWS>
__global__ void __launch_bounds__(256) gemm_f32(
    const float* __restrict__ X, const float* __restrict__ W,
    const float* __restrict__ bias, float* __restrict__ outp, int N) {
  __shared__ float xs[Cc][ROWS];
  const int tx = threadIdx.x;
  const int r0 = blockIdx.x * ROWS;
  const int o0 = blockIdx.y * 768 + tx;
  for (int idx = tx; idx < ROWS * Cc; idx += 256) {
    const int r = idx / Cc, c = idx - r * Cc;
    xs[c][r] = X[(size_t)(r0 + r) * Cc + c];
  }
  __syncthreads();
  float acc0[ROWS], acc1[ROWS], acc2[ROWS];
  const float b0 = bias[o0], b1 = bias[o0 + 256], b2 = bias[o0 + 512];
#pragma unroll
  for (int r = 0; r < ROWS; ++r) { acc0[r] = b0; acc1[r] = b1; acc2[r] = b2; }
#pragma unroll 4
  for (int c = 0; c < Cc; ++c) {
    const size_t wrow = (size_t)c * N + o0;
    const float w0 = W[wrow];
    const float w1 = W[wrow + 256];
    const float w2 = W[wrow + 512];
    const float4* xv = reinterpret_cast<const float4*>(&xs[c][0]);
#pragma unroll
    for (int q = 0; q < ROWS / 4; ++q) {
      const float4 x4 = xv[q];
      const float xr[4] = {x4.x, x4.y, x4.z, x4.w};
#pragma unroll
      for (int u = 0; u < 4; ++u) {
        const int r = q * 4 + u;
        acc0[r] += xr[u] * w0;
        acc1[r] += xr[u] * w1;
        acc2[r] += xr[u] * w2;
      }
    }
  }
#pragma unroll
  for (int r = 0; r < ROWS; ++r) {
    const size_t orow = (size_t)(r0 + r) * N + o0;
    outp[orow]       = acc0[r];
    outp[orow + 256] = acc1[r];
    outp[orow + 512] = acc2[r];
  }
}

// ---------------------------------------------------------------------------
// S[bh][i][j] = q_i . k_j (fp32), -inf where j > i. 64x64 tiles.
// ---------------------------------------------------------------------------
__global__ void __launch_bounds__(256) sims_kernel(
    const float* __restrict__ qkv, float* __restrict__ S) {
  const int jt = blockIdx.x, it = blockIdx.y, bh = blockIdx.z;
  const int b = bh / Hc, h = bh % Hc;
  const int tx = threadIdx.x;
  const int j = tx & 63, iq = tx >> 6;
  float* Shead = S + (size_t)bh * Tc * Tc;
  if (jt > it) {
#pragma unroll
    for (int r = 0; r < 16; ++r) {
      const int i = it * 64 + iq * 16 + r;
      Shead[(size_t)i * Tc + jt * 64 + j] = -INFINITY;
    }
    return;
  }
  __shared__ float qs[64][65], ks[64][65];
  const float* base = qkv + (size_t)b * Tc * QKVN + h * HSc;
  for (int idx = tx; idx < 4096; idx += 256) {
    const int r = idx >> 6, d = idx & 63;
    qs[r][d] = base[(size_t)(it * 64 + r) * QKVN + d];
    ks[r][d] = base[(size_t)(jt * 64 + r) * QKVN + Cc + d];
  }
  __syncthreads();
  float acc[16];
#pragma unroll
  for (int r = 0; r < 16; ++r) acc[r] = 0.0f;
  for (int d = 0; d < HSc; ++d) {
    const float kv = ks[j][d];
#pragma unroll
    for (int r = 0; r < 16; ++r)
      acc[r] += qs[iq * 16 + r][d] * kv;
  }
#pragma unroll
  for (int r = 0; r < 16; ++r) {
    const int i = it * 64 + iq * 16 + r;
    const int jj = jt * 64 + j;
    Shead[(size_t)i * Tc + jj] = (jj <= i) ? acc[r] : -INFINITY;
  }
}

// ---------------------------------------------------------------------------
// Greedy DPP selection, 4 tokens/wave, incremental-Cholesky scoring:
//   det(G_{S u c}) = detS * schur_c,  schur_c = ||k_c||^2 - sum_t z_c[t]^2,
//   on accept of b (as t-th selected): z_c[t] = (k_c.k_b - <z_c,z_b>)/d_b.
// Accepts are consecutive (first reject -> done forever), so count == it+1 on
// every accept path -> all z indices static under full unroll (registers only).
// Deviation vs the reference's LU det is ~1e-15 rel; the reference itself
// casts grams to float32 before det and we matched its decisions with fp64 LU
// for 3 rounds -> margins tolerate >=1e-7. Safe.
// ---------------------------------------------------------------------------
__global__ void __launch_bounds__(64, 4) select4_kernel(
    const float* __restrict__ qkv, const float* __restrict__ S,
    float* __restrict__ y) {
  const int bid = blockIdx.x;          // 4 tokens per block
  const int bh = bid >> 7;             // 128 blocks per (b,h)
  const int i0 = (bid & 127) << 2;
  const int b = bh / Hc;
  const int h = bh % Hc;
  const int lane = threadIdx.x;
  const int g = lane >> 4;             // token group 0..3
  const int l16 = lane & 15;
  const int i_g = i0 + g;

  const float* base = qkv + (size_t)b * Tc * QKVN + h * HSc;
  const float* kbase = base + Cc;
  const float* vbase = base + 2 * Cc;

  __shared__ float Kc[4][17][68];      // cands 0..15 + k_i at 16; pad 68
  __shared__ int topidxS[4][16];
  __shared__ int selS[4][8];

  // ---- phase 1: load sims row; build sortable u64 keys ----
  // key = (sortable(float) << 32) | (511 - j): max key == max val, tie -> low j
  const float* Srow = S + ((size_t)bh * Tc + i_g) * Tc;
  const float4* Sq = reinterpret_cast<const float4*>(Srow);
  unsigned long long key[32];
#pragma unroll
  for (int r4 = 0; r4 < 8; ++r4) {
    const float4 v4 = Sq[l16 * 8 + r4];
    const float vv[4] = {v4.x, v4.y, v4.z, v4.w};
#pragma unroll
    for (int c = 0; c < 4; ++c) {
      const int j = l16 * 32 + r4 * 4 + c;
      const unsigned u = __float_as_uint(vv[c]);
      const unsigned s = (u & 0x80000000u) ? ~u : (u | 0x80000000u);
      key[r4 * 4 + c] = ((unsigned long long)s << 32) | (unsigned)(511 - j);
    }
  }

  // ---- phase 2: top-16 per group (exact jax.lax.top_k semantics) ----
  unsigned avail = 0;
  for (int m = 0; m < 16; ++m) {
    unsigned long long bk = 0;
#pragma unroll
    for (int r = 0; r < 32; ++r) bk = (key[r] > bk) ? key[r] : bk;
#pragma unroll
    for (int msk = 1; msk <= 8; msk <<= 1) {
      const unsigned long long ok = __shfl_xor(bk, msk);
      bk = (ok > bk) ? ok : bk;
    }
    const int j = 511 - (int)(unsigned)(bk & 0xFFFFFFFFull);
    const unsigned shi = (unsigned)(bk >> 32);
    if (l16 == 0) topidxS[g][m] = j;
    if (shi > 0x007FFFFFu && j != i_g) avail |= (1u << m);  // finite && != i
#pragma unroll
    for (int r = 0; r < 32; ++r) key[r] = (key[r] == bk) ? 0ull : key[r];
  }
  __syncthreads();

  // ---- phase 3: gather candidate k-rows + k_i into LDS (coalesced) ----
#pragma unroll
  for (int g2 = 0; g2 < 4; ++g2)
    for (int m2 = 0; m2 < 17; ++m2) {
      const int j = (m2 < 16) ? topidxS[g2][m2] : (i0 + g2);
      Kc[g2][m2][lane] = kbase[(size_t)j * QKVN + lane];
    }
  __syncthreads();

  // ---- phase 4: cnorm, z0, kii (f64 dots from LDS) ----
  const float4* myrow = reinterpret_cast<const float4*>(&Kc[g][l16][0]);
  const float4* irow  = reinterpret_cast<const float4*>(&Kc[g][16][0]);
  double cnorm = 0.0, c0 = 0.0, kii = 0.0;
#pragma unroll
  for (int q = 0; q < 16; ++q) {
    const float4 a4 = myrow[q];
    const float4 i4 = irow[q];
    cnorm += (double)a4.x * a4.x; cnorm += (double)a4.y * a4.y;
    cnorm += (double)a4.z * a4.z; cnorm += (double)a4.w * a4.w;
    c0    += (double)a4.x * i4.x; c0    += (double)a4.y * i4.y;
    c0    += (double)a4.z * i4.z; c0    += (double)a4.w * i4.w;
    kii   += (double)i4.x * i4.x; kii   += (double)i4.y * i4.y;
    kii   += (double)i4.z * i4.z; kii   += (double)i4.w * i4.w;
  }
  double z[8];
#pragma unroll
  for (int t = 0; t < 8; ++t) z[t] = 0.0;
  z[0] = c0 / sqrt(kii);
  double schur = cnorm - z[0] * z[0];
  double detS = kii;
  double cur_s = -log(kii + EPSd);
  int count = 1;
  bool done = false;
  if (l16 == 0) selS[g][0] = i_g;

  // ---- phase 5: greedy loop, fully unrolled (static z indices) ----
#pragma unroll
  for (int it = 0; it < 7; ++it) {
    if (__ballot(done) != ~0ull) {
      const double D = detS * schur + EPSd;
      const double sval = -log(D) / (double)(it + 2);
      const bool act = (!done) && ((avail >> l16) & 1u);
      const double sorig = act ? sval : -INFINITY;
      // group argmax; NaN acts as max (numpy argmax), ties -> lower m
      double bkey = __builtin_isnan(sorig) ? INFINITY : sorig;
      int bm = l16;
#pragma unroll
      for (int msk = 1; msk <= 8; msk <<= 1) {
        const double ok2 = __shfl_xor(bkey, msk);
        const int om = __shfl_xor(bm, msk);
        const bool t2 = (ok2 > bkey) || (ok2 == bkey && om < bm);
        bkey = t2 ? ok2 : bkey;
        bm = t2 ? om : bm;
      }
      const int srcl = (g << 4) | bm;
      const double best_s = __shfl(sorig, srcl);   // original (maybe NaN)
      const bool X = (avail != 0u) && ((best_s > cur_s) || (it == 0));
      const bool accept = (!done) && X;
      // broadcast z_b, schur_b (outside the divergent if)
      const double schur_b = __shfl(schur, srcl);
      double sum = 0.0;
#pragma unroll
      for (int t = 0; t <= it; ++t) {
        const double zbt = __shfl(z[t], srcl);
        sum += z[t] * zbt;
      }
      if (accept) {
        const float4* brow = reinterpret_cast<const float4*>(&Kc[g][bm][0]);
        double cp = 0.0;
#pragma unroll
        for (int q = 0; q < 16; ++q) {
          const float4 a4 = myrow[q];
          const float4 b4 = brow[q];
          cp += (double)a4.x * b4.x; cp += (double)a4.y * b4.y;
          cp += (double)a4.z * b4.z; cp += (double)a4.w * b4.w;
        }
        const double znew = (cp - sum) / sqrt(schur_b);
        z[it + 1] = znew;
        schur -= znew * znew;
        detS *= schur_b;
        cur_s = best_s;
        avail &= ~(1u << bm);
        ++count;
        if (l16 == 0) selS[g][it + 1] = topidxS[g][bm];
      }
      done = done || (!X);
    }
  }
  __syncthreads();

  // ---- phase 6: output = mean of selected v rows; y is [B,T,H,HS] ----
#pragma unroll
  for (int g2 = 0; g2 < 4; ++g2) {
    const int cnt = __shfl(count, g2 << 4);
    double acc = 0.0;
#pragma unroll
    for (int a = 0; a < 8; ++a)
      if (a < cnt) acc += (double)vbase[(size_t)selS[g2][a] * QKVN + lane];
    y[(((size_t)b * Tc + (i0 + g2)) * Hc + h) * HSc + lane] =
        (float)(acc / (double)cnt);
  }
}

// ---------------------------------------------------------------------------
extern "C" void kernel_launch(void* const* d_in, const int* in_sizes, int n_in,
                              void* d_out, int out_size, void* d_ws, size_t ws_size,
                              hipStream_t stream) {
  (void)in_sizes; (void)n_in; (void)out_size; (void)ws_size;
  const float* x  = (const float*)d_in[0];
  const float* Wa = (const float*)d_in[1];
  const float* ba = (const float*)d_in[2];
  const float* Wp = (const float*)d_in[3];
  const float* bp = (const float*)d_in[4];
  float* out = (float*)d_out;

  float* qkv = (float*)d_ws;                          // [B*T][2304] fp32, 18.9MB
  float* y   = qkv + (size_t)Bc * Tc * QKVN;          // [B*T][768]  fp32,  6.3MB
  float* S   = y + (size_t)Bc * Tc * Cc;              // [48][512][512],   50.3MB

  // 1) qkv = x @ W_attn + b_attn (fp32, all 2304 cols)
  hipLaunchKernelGGL((gemm_f32<16>), dim3((Bc * Tc) / 16, 3), dim3(256), 0,
                     stream, x, Wa, ba, qkv, QKVN);
  // 2) S = Q K^T per head, causal -inf (fp32)
  hipLaunchKernelGGL(sims_kernel, dim3(8, 8, Bc * Hc), dim3(256), 0,
                     stream, qkv, S);
  // 3) greedy DPP, 4 tokens/wave, incremental Cholesky
  hipLaunchKernelGGL(select4_kernel, dim3(Bc * Hc * Tc / 4), dim3(64), 0,
                     stream, qkv, S, y);
  // 4) out = y @ W_proj + b_proj (fp32)
  hipLaunchKernelGGL((gemm_f32<8>), dim3((Bc * Tc) / 8, 1), dim3(256), 0,
                     stream, y, Wp, bp, out, Cc);
}

// Round 5
// 440.343 us; speedup vs baseline: 2.4660x; 1.1367x over previous
//
#include <hip/hip_runtime.h>
#include <math.h>

// Problem constants (from reference):
constexpr int Bc = 4, Tc = 512, Cc = 768, Hc = 12, HSc = 64;
constexpr int QKVN = 3 * Cc;  // 2304
constexpr double EPSd = 1e-6;

// ---------------------------------------------------------------------------
// LDS-tiled fp32 GEMM: C[M,N] = X[M,768] @ W[768,N] + bias. BK=16.
// 256 threads; thread computes TM x TN. As stored [k][m] (pad +4), Bs [k][n]
// (pad +4) -> 2-way-max bank aliasing (free on CDNA4).
// fp32 is decision-safe per R4 evidence (zero flips with fp32 q,k,S).
// ---------------------------------------------------------------------------
template <int BM, int BN, int TM, int TN>
__global__ void __launch_bounds__(256) gemm_tiled(
    const float* __restrict__ X, const float* __restrict__ W,
    const float* __restrict__ bias, float* __restrict__ outp, int N) {
  constexpr int BK = 16;
  __shared__ float As[BK][BM + 4];
  __shared__ float Bs[BK][BN + 4];
  const int tid = threadIdx.x;
  const int tx = tid % (BN / TN);
  const int ty = tid / (BN / TN);
  const int rb = blockIdx.x * BM;
  const int cb = blockIdx.y * BN;
  float acc[TM][TN];
#pragma unroll
  for (int m = 0; m < TM; ++m)
#pragma unroll
    for (int n = 0; n < TN; ++n) acc[m][n] = 0.0f;

  for (int k0 = 0; k0 < Cc; k0 += BK) {
    constexpr int AF4 = BM * BK / 4;
#pragma unroll
    for (int f = tid; f < AF4; f += 256) {
      const int row = f >> 2, k4 = (f & 3) * 4;
      const float4 a4 =
          *(const float4*)&X[(size_t)(rb + row) * Cc + k0 + k4];
      As[k4 + 0][row] = a4.x;
      As[k4 + 1][row] = a4.y;
      As[k4 + 2][row] = a4.z;
      As[k4 + 3][row] = a4.w;
    }
    constexpr int BF4 = BK * BN / 4;
#pragma unroll
    for (int f = tid; f < BF4; f += 256) {
      const int kk = f / (BN / 4), n4 = (f % (BN / 4)) * 4;
      *(float4*)&Bs[kk][n4] =
          *(const float4*)&W[(size_t)(k0 + kk) * N + cb + n4];
    }
    __syncthreads();
#pragma unroll
    for (int kk = 0; kk < BK; ++kk) {
      float a[TM], bv[TN];
#pragma unroll
      for (int m4 = 0; m4 < TM / 4; ++m4) {
        const float4 a4 = *(const float4*)&As[kk][ty * TM + m4 * 4];
        a[m4 * 4 + 0] = a4.x; a[m4 * 4 + 1] = a4.y;
        a[m4 * 4 + 2] = a4.z; a[m4 * 4 + 3] = a4.w;
      }
#pragma unroll
      for (int n4 = 0; n4 < TN / 4; ++n4) {
        const float4 b4 = *(const float4*)&Bs[kk][tx * TN + n4 * 4];
        bv[n4 * 4 + 0] = b4.x; bv[n4 * 4 + 1] = b4.y;
        bv[n4 * 4 + 2] = b4.z; bv[n4 * 4 + 3] = b4.w;
      }
#pragma unroll
      for (int m = 0; m < TM; ++m)
#pragma unroll
        for (int n = 0; n < TN; ++n) acc[m][n] += a[m] * bv[n];
    }
    __syncthreads();
  }
#pragma unroll
  for (int m = 0; m < TM; ++m) {
    const size_t orow = (size_t)(rb + ty * TM + m) * N + cb + tx * TN;
#pragma unroll
    for (int n4 = 0; n4 < TN / 4; ++n4) {
      float4 o4;
      o4.x = acc[m][n4 * 4 + 0] + bias[cb + tx * TN + n4 * 4 + 0];
      o4.y = acc[m][n4 * 4 + 1] + bias[cb + tx * TN + n4 * 4 + 1];
      o4.z = acc[m][n4 * 4 + 2] + bias[cb + tx * TN + n4 * 4 + 2];
      o4.w = acc[m][n4 * 4 + 3] + bias[cb + tx * TN + n4 * 4 + 3];
      *(float4*)&outp[orow + n4 * 4] = o4;
    }
  }
}

// ---------------------------------------------------------------------------
// S[bh][i][j] = q_i . k_j (fp32), -inf where j > i. 64x64 tiles.
// ---------------------------------------------------------------------------
__global__ void __launch_bounds__(256) sims_kernel(
    const float* __restrict__ qkv, float* __restrict__ S) {
  const int jt = blockIdx.x, it = blockIdx.y, bh = blockIdx.z;
  const int b = bh / Hc, h = bh % Hc;
  const int tx = threadIdx.x;
  const int j = tx & 63, iq = tx >> 6;
  float* Shead = S + (size_t)bh * Tc * Tc;
  if (jt > it) {
#pragma unroll
    for (int r = 0; r < 16; ++r) {
      const int i = it * 64 + iq * 16 + r;
      Shead[(size_t)i * Tc + jt * 64 + j] = -INFINITY;
    }
    return;
  }
  __shared__ float qs[64][65], ks[64][65];
  const float* base = qkv + (size_t)b * Tc * QKVN + h * HSc;
  for (int idx = tx; idx < 4096; idx += 256) {
    const int r = idx >> 6, d = idx & 63;
    qs[r][d] = base[(size_t)(it * 64 + r) * QKVN + d];
    ks[r][d] = base[(size_t)(jt * 64 + r) * QKVN + Cc + d];
  }
  __syncthreads();
  float acc[16];
#pragma unroll
  for (int r = 0; r < 16; ++r) acc[r] = 0.0f;
  for (int d = 0; d < HSc; ++d) {
    const float kv = ks[j][d];
#pragma unroll
    for (int r = 0; r < 16; ++r)
      acc[r] += qs[iq * 16 + r][d] * kv;
  }
#pragma unroll
  for (int r = 0; r < 16; ++r) {
    const int i = it * 64 + iq * 16 + r;
    const int jj = jt * 64 + j;
    Shead[(size_t)i * Tc + jj] = (jj <= i) ? acc[r] : -INFINITY;
  }
}

// ---------------------------------------------------------------------------
// Top-16 per token row, one full wave per token (4 waves/block). 8 u64 keys
// per lane (16 VGPRs). key = (sortable(f32)<<32)|(511-j): exact jax.lax.top_k
// semantics (descending, ties -> lower index). Writes topidx[tok][16] and a
// 16-bit avail mask (finite && j != i).
// ---------------------------------------------------------------------------
__global__ void __launch_bounds__(256) topk_kernel(
    const float* __restrict__ S, int* __restrict__ topidx,
    unsigned* __restrict__ availB) {
  const int tid = threadIdx.x;
  const int wv = tid >> 6, lane = tid & 63;
  const int tok = blockIdx.x * 4 + wv;  // bh*512 + i
  const int i = tok & (Tc - 1);
  const float4* Sq = reinterpret_cast<const float4*>(S + (size_t)tok * Tc);
  unsigned long long key[8];
#pragma unroll
  for (int r = 0; r < 2; ++r) {
    const float4 v4 = Sq[lane * 2 + r];
    const float vv[4] = {v4.x, v4.y, v4.z, v4.w};
#pragma unroll
    for (int c = 0; c < 4; ++c) {
      const int j = lane * 8 + r * 4 + c;
      const unsigned u = __float_as_uint(vv[c]);
      const unsigned s = (u & 0x80000000u) ? ~u : (u | 0x80000000u);
      key[r * 4 + c] = ((unsigned long long)s << 32) | (unsigned)(511 - j);
    }
  }
  unsigned avail = 0;
  for (int m = 0; m < 16; ++m) {
    unsigned long long bk = 0;
#pragma unroll
    for (int r = 0; r < 8; ++r) bk = (key[r] > bk) ? key[r] : bk;
#pragma unroll
    for (int msk = 1; msk <= 32; msk <<= 1) {
      const unsigned long long ok = __shfl_xor(bk, msk);
      bk = (ok > bk) ? ok : bk;
    }
    const int j = 511 - (int)(unsigned)(bk & 0xFFFFFFFFull);
    const unsigned shi = (unsigned)(bk >> 32);
    if (lane == 0) topidx[(size_t)tok * 16 + m] = j;
    if (shi > 0x007FFFFFu && j != i) avail |= (1u << m);
#pragma unroll
    for (int r = 0; r < 8; ++r) key[r] = (key[r] == bk) ? 0ull : key[r];
  }
  if (lane == 0) availB[tok] = avail;
}

// ---------------------------------------------------------------------------
// Greedy DPP selection, 4 tokens/wave, incremental-Cholesky scoring (as R4 —
// bit-identical decision math). Top-16 precomputed -> VGPR/instr load drops.
// ---------------------------------------------------------------------------
__global__ void __launch_bounds__(64, 4) select4_kernel(
    const float* __restrict__ qkv, const int* __restrict__ topidx,
    const unsigned* __restrict__ availB, float* __restrict__ y) {
  const int bid = blockIdx.x;          // 4 tokens per block
  const int bh = bid >> 7;             // 128 blocks per (b,h)
  const int i0 = (bid & 127) << 2;
  const int b = bh / Hc;
  const int h = bh % Hc;
  const int lane = threadIdx.x;
  const int g = lane >> 4;             // token group 0..3
  const int l16 = lane & 15;
  const int i_g = i0 + g;
  const int tok0 = bh * Tc + i0;

  const float* base = qkv + (size_t)b * Tc * QKVN + h * HSc;
  const float* kbase = base + Cc;
  const float* vbase = base + 2 * Cc;

  __shared__ float Kc[4][17][68];      // cands 0..15 + k_i at 16; pad 68
  __shared__ int topidxS[4][16];
  __shared__ int selS[4][8];

  // ---- load precomputed top-16 + avail ----
  topidxS[lane >> 4][lane & 15] =
      topidx[(size_t)(tok0 + (lane >> 4)) * 16 + (lane & 15)];
  unsigned avail = availB[tok0 + g];
  __syncthreads();

  // ---- gather candidate k-rows + k_i into LDS (coalesced) ----
#pragma unroll
  for (int g2 = 0; g2 < 4; ++g2)
    for (int m2 = 0; m2 < 17; ++m2) {
      const int j = (m2 < 16) ? topidxS[g2][m2] : (i0 + g2);
      Kc[g2][m2][lane] = kbase[(size_t)j * QKVN + lane];
    }
  __syncthreads();

  // ---- cnorm, z0, kii (f64 dots from LDS) ----
  const float4* myrow = reinterpret_cast<const float4*>(&Kc[g][l16][0]);
  const float4* irow  = reinterpret_cast<const float4*>(&Kc[g][16][0]);
  double cnorm = 0.0, c0 = 0.0, kii = 0.0;
#pragma unroll
  for (int q = 0; q < 16; ++q) {
    const float4 a4 = myrow[q];
    const float4 i4 = irow[q];
    cnorm += (double)a4.x * a4.x; cnorm += (double)a4.y * a4.y;
    cnorm += (double)a4.z * a4.z; cnorm += (double)a4.w * a4.w;
    c0    += (double)a4.x * i4.x; c0    += (double)a4.y * i4.y;
    c0    += (double)a4.z * i4.z; c0    += (double)a4.w * i4.w;
    kii   += (double)i4.x * i4.x; kii   += (double)i4.y * i4.y;
    kii   += (double)i4.z * i4.z; kii   += (double)i4.w * i4.w;
  }
  double z[8];
#pragma unroll
  for (int t = 0; t < 8; ++t) z[t] = 0.0;
  z[0] = c0 / sqrt(kii);
  double schur = cnorm - z[0] * z[0];
  double detS = kii;
  double cur_s = -log(kii + EPSd);
  int count = 1;
  bool done = false;
  if (l16 == 0) selS[g][0] = i_g;

  // ---- greedy loop, fully unrolled (static z indices) ----
#pragma unroll
  for (int it = 0; it < 7; ++it) {
    if (__ballot(done) != ~0ull) {
      const double D = detS * schur + EPSd;
      const double sval = -log(D) / (double)(it + 2);
      const bool act = (!done) && ((avail >> l16) & 1u);
      const double sorig = act ? sval : -INFINITY;
      // group argmax; NaN acts as max (numpy argmax), ties -> lower m
      double bkey = __builtin_isnan(sorig) ? INFINITY : sorig;
      int bm = l16;
#pragma unroll
      for (int msk = 1; msk <= 8; msk <<= 1) {
        const double ok2 = __shfl_xor(bkey, msk);
        const int om = __shfl_xor(bm, msk);
        const bool t2 = (ok2 > bkey) || (ok2 == bkey && om < bm);
        bkey = t2 ? ok2 : bkey;
        bm = t2 ? om : bm;
      }
      const int srcl = (g << 4) | bm;
      const double best_s = __shfl(sorig, srcl);   // original (maybe NaN)
      const bool X = (avail != 0u) && ((best_s > cur_s) || (it == 0));
      const bool accept = (!done) && X;
      // broadcast z_b, schur_b (outside the divergent if)
      const double schur_b = __shfl(schur, srcl);
      double sum = 0.0;
#pragma unroll
      for (int t = 0; t <= it; ++t) {
        const double zbt = __shfl(z[t], srcl);
        sum += z[t] * zbt;
      }
      if (accept) {
        const float4* brow = reinterpret_cast<const float4*>(&Kc[g][bm][0]);
        double cp = 0.0;
#pragma unroll
        for (int q = 0; q < 16; ++q) {
          const float4 a4 = myrow[q];
          const float4 b4 = brow[q];
          cp += (double)a4.x * b4.x; cp += (double)a4.y * b4.y;
          cp += (double)a4.z * b4.z; cp += (double)a4.w * b4.w;
        }
        const double znew = (cp - sum) / sqrt(schur_b);
        z[it + 1] = znew;
        schur -= znew * znew;
        detS *= schur_b;
        cur_s = best_s;
        avail &= ~(1u << bm);
        ++count;
        if (l16 == 0) selS[g][it + 1] = topidxS[g][bm];
      }
      done = done || (!X);
    }
  }
  __syncthreads();

  // ---- output = mean of selected v rows; y is [B,T,H,HS] ----
#pragma unroll
  for (int g2 = 0; g2 < 4; ++g2) {
    const int cnt = __shfl(count, g2 << 4);
    double acc = 0.0;
#pragma unroll
    for (int a = 0; a < 8; ++a)
      if (a < cnt) acc += (double)vbase[(size_t)selS[g2][a] * QKVN + lane];
    y[(((size_t)b * Tc + (i0 + g2)) * Hc + h) * HSc + lane] =
        (float)(acc / (double)cnt);
  }
}

// ---------------------------------------------------------------------------
extern "C" void kernel_launch(void* const* d_in, const int* in_sizes, int n_in,
                              void* d_out, int out_size, void* d_ws, size_t ws_size,
                              hipStream_t stream) {
  (void)in_sizes; (void)n_in; (void)out_size; (void)ws_size;
  const float* x  = (const float*)d_in[0];
  const float* Wa = (const float*)d_in[1];
  const float* ba = (const float*)d_in[2];
  const float* Wp = (const float*)d_in[3];
  const float* bp = (const float*)d_in[4];
  float* out = (float*)d_out;

  float* qkv = (float*)d_ws;                          // [B*T][2304]  18.9MB
  float* y   = qkv + (size_t)Bc * Tc * QKVN;          // [B*T][768]    6.3MB
  float* S   = y + (size_t)Bc * Tc * Cc;              // [48][512][512] 50.3MB
  int* topidx = (int*)(S + (size_t)Bc * Hc * Tc * Tc);     // [24576][16] 1.6MB
  unsigned* availB = (unsigned*)(topidx + (size_t)Bc * Hc * Tc * 16);  // 98KB

  // 1) qkv = x @ W_attn + b_attn (fp32 tiled)
  hipLaunchKernelGGL((gemm_tiled<128, 64, 8, 4>),
                     dim3((Bc * Tc) / 128, QKVN / 64), dim3(256), 0,
                     stream, x, Wa, ba, qkv, QKVN);
  // 2) S = Q K^T per head, causal -inf (fp32)
  hipLaunchKernelGGL(sims_kernel, dim3(8, 8, Bc * Hc), dim3(256), 0,
                     stream, qkv, S);
  // 3) top-16 per token (one wave per token)
  hipLaunchKernelGGL(topk_kernel, dim3(Bc * Hc * Tc / 4), dim3(256), 0,
                     stream, S, topidx, availB);
  // 4) greedy DPP, 4 tokens/wave, incremental Cholesky
  hipLaunchKernelGGL(select4_kernel, dim3(Bc * Hc * Tc / 4), dim3(64), 0,
                     stream, qkv, topidx, availB, y);
  // 5) out = y @ W_proj + b_proj (fp32 tiled)
  hipLaunchKernelGGL((gemm_tiled<64, 64, 4, 4>),
                     dim3((Bc * Tc) / 64, Cc / 64), dim3(256), 0,
                     stream, y, Wp, bp, out, Cc);
}

// Round 6
// 429.707 us; speedup vs baseline: 2.5271x; 1.0248x over previous
//
#include <hip/hip_runtime.h>
#include <math.h>

// Problem constants (from reference):
constexpr int Bc = 4, Tc = 512, Cc = 768, Hc = 12, HSc = 64;
constexpr int QKVN = 3 * Cc;  // 2304
constexpr double EPSd = 1e-6;

// ---------------------------------------------------------------------------
// LDS-tiled fp32 GEMM: C[M,N] = X[M,768] @ W[768,N] + bias. BK=8.
// As stored TRANSPOSED [k][m] -> a-fragment reads are wave-broadcast b128.
// Thread computes TM x TN (TM,TN multiples of 4). 256 threads.
// fp32 is decision-safe per R4/R5 evidence (zero flips with fp32 q,k,S).
// ---------------------------------------------------------------------------
template <int BM, int BN, int TM, int TN>
__global__ void __launch_bounds__(256) gemm_tiled(
    const float* __restrict__ X, const float* __restrict__ W,
    const float* __restrict__ bias, float* __restrict__ outp, int N) {
  constexpr int BK = 8;
  __shared__ float As[BK][BM + 4];
  __shared__ float Bs[BK][BN + 4];
  const int tid = threadIdx.x;
  const int tx = tid % (BN / TN);
  const int ty = tid / (BN / TN);
  const int rb = blockIdx.x * BM;
  const int cb = blockIdx.y * BN;
  float acc[TM][TN];
#pragma unroll
  for (int m = 0; m < TM; ++m)
#pragma unroll
    for (int n = 0; n < TN; ++n) acc[m][n] = 0.0f;

  for (int k0 = 0; k0 < Cc; k0 += BK) {
    // stage A (BM x BK, transposed into As[k][m])
    constexpr int NF2 = BM * BK / 2;
#pragma unroll
    for (int f = tid; f < NF2; f += 256) {
      const int row = f / (BK / 2);
      const int k2 = (f % (BK / 2)) * 2;
      const float2 a2 = *(const float2*)&X[(size_t)(rb + row) * Cc + k0 + k2];
      As[k2][row] = a2.x;
      As[k2 + 1][row] = a2.y;
    }
    // stage B (BK x BN, coalesced)
    constexpr int NF4 = BK * BN / 4;
#pragma unroll
    for (int f = tid; f < NF4; f += 256) {
      const int kk = f / (BN / 4);
      const int n4 = (f % (BN / 4)) * 4;
      *(float4*)&Bs[kk][n4] =
          *(const float4*)&W[(size_t)(k0 + kk) * N + cb + n4];
    }
    __syncthreads();
#pragma unroll
    for (int kk = 0; kk < BK; ++kk) {
      float a[TM], bv[TN];
#pragma unroll
      for (int m4 = 0; m4 < TM / 4; ++m4) {
        const float4 a4 = *(const float4*)&As[kk][ty * TM + m4 * 4];
        a[m4 * 4 + 0] = a4.x; a[m4 * 4 + 1] = a4.y;
        a[m4 * 4 + 2] = a4.z; a[m4 * 4 + 3] = a4.w;
      }
#pragma unroll
      for (int n4 = 0; n4 < TN / 4; ++n4) {
        const float4 b4 = *(const float4*)&Bs[kk][tx * TN + n4 * 4];
        bv[n4 * 4 + 0] = b4.x; bv[n4 * 4 + 1] = b4.y;
        bv[n4 * 4 + 2] = b4.z; bv[n4 * 4 + 3] = b4.w;
      }
#pragma unroll
      for (int m = 0; m < TM; ++m)
#pragma unroll
        for (int n = 0; n < TN; ++n) acc[m][n] += a[m] * bv[n];
    }
    __syncthreads();
  }
  float bb[TN];
#pragma unroll
  for (int n = 0; n < TN; ++n) bb[n] = bias[cb + tx * TN + n];
#pragma unroll
  for (int m = 0; m < TM; ++m) {
    const size_t orow = (size_t)(rb + ty * TM + m) * N + cb + tx * TN;
#pragma unroll
    for (int n4 = 0; n4 < TN / 4; ++n4) {
      float4 o4;
      o4.x = acc[m][n4 * 4 + 0] + bb[n4 * 4 + 0];
      o4.y = acc[m][n4 * 4 + 1] + bb[n4 * 4 + 1];
      o4.z = acc[m][n4 * 4 + 2] + bb[n4 * 4 + 2];
      o4.w = acc[m][n4 * 4 + 3] + bb[n4 * 4 + 3];
      *(float4*)&outp[orow + n4 * 4] = o4;
    }
  }
}

// ---------------------------------------------------------------------------
// S[bh][i][j] = q_i . k_j (fp32). LOWER-TRIANGLE TILES ONLY (36 of 64 per
// head); j>i entries (incl. diagonal-tile upper part) are left as-is and
// masked inside topk_kernel. GEMM-style: 64x64x64 tile, 4x4 register tile,
// operands transposed [d][token] in LDS for b128 fragment reads.
// ---------------------------------------------------------------------------
__global__ void __launch_bounds__(256) sims_kernel(
    const float* __restrict__ qkv, float* __restrict__ S) {
  const int bh = blockIdx.y;
  const int b = bh / Hc, h = bh % Hc;
  int it = 0;
  {
    const int t = blockIdx.x;
    while ((it + 1) * (it + 2) / 2 <= t) ++it;
    // jt computed below from t
  }
  const int jt = blockIdx.x - it * (it + 1) / 2;
  const int tid = threadIdx.x;
  const int tx = tid & 15, ty = tid >> 4;
  __shared__ float Qs[HSc][68];  // Qs[d][i_local]
  __shared__ float Ks[HSc][68];  // Ks[d][j_local]
  const float* base = qkv + (size_t)b * Tc * QKVN + h * HSc;
  {
    const int row = tid >> 2;        // 0..63
    const int d0 = (tid & 3) * 16;   // 0,16,32,48
    const float* qrow = base + (size_t)(it * 64 + row) * QKVN;
    const float* krow = base + (size_t)(jt * 64 + row) * QKVN + Cc;
#pragma unroll
    for (int u = 0; u < 4; ++u) {
      const float4 q4 = *(const float4*)&qrow[d0 + u * 4];
      const float4 k4 = *(const float4*)&krow[d0 + u * 4];
      Qs[d0 + u * 4 + 0][row] = q4.x; Qs[d0 + u * 4 + 1][row] = q4.y;
      Qs[d0 + u * 4 + 2][row] = q4.z; Qs[d0 + u * 4 + 3][row] = q4.w;
      Ks[d0 + u * 4 + 0][row] = k4.x; Ks[d0 + u * 4 + 1][row] = k4.y;
      Ks[d0 + u * 4 + 2][row] = k4.z; Ks[d0 + u * 4 + 3][row] = k4.w;
    }
  }
  __syncthreads();
  float acc[4][4];
#pragma unroll
  for (int m = 0; m < 4; ++m)
#pragma unroll
    for (int n = 0; n < 4; ++n) acc[m][n] = 0.0f;
#pragma unroll 4
  for (int d = 0; d < HSc; ++d) {
    const float4 a4 = *(const float4*)&Qs[d][ty * 4];
    const float4 b4 = *(const float4*)&Ks[d][tx * 4];
    const float a[4] = {a4.x, a4.y, a4.z, a4.w};
    const float bv[4] = {b4.x, b4.y, b4.z, b4.w};
#pragma unroll
    for (int m = 0; m < 4; ++m)
#pragma unroll
      for (int n = 0; n < 4; ++n) acc[m][n] += a[m] * bv[n];
  }
  float* Shead = S + (size_t)bh * Tc * Tc;
#pragma unroll
  for (int m = 0; m < 4; ++m) {
    const int i = it * 64 + ty * 4 + m;
    float4 o4 = {acc[m][0], acc[m][1], acc[m][2], acc[m][3]};
    *(float4*)&Shead[(size_t)i * Tc + jt * 64 + tx * 4] = o4;
  }
}

// ---------------------------------------------------------------------------
// Top-16 per token row, one full wave per token. key=(sortable(f32)<<32)|
// (511-j) -> exact jax.lax.top_k semantics. j>i masked here (key=0): for
// i>=15 identical to -inf fill (top-16 all causal); for i<15 the padding
// slots have avail=0 either way (topidx value then never used for selection).
// ---------------------------------------------------------------------------
__global__ void __launch_bounds__(256) topk_kernel(
    const float* __restrict__ S, int* __restrict__ topidx,
    unsigned* __restrict__ availB) {
  const int tid = threadIdx.x;
  const int wv = tid >> 6, lane = tid & 63;
  const int tok = blockIdx.x * 4 + wv;  // bh*512 + i
  const int i = tok & (Tc - 1);
  const float4* Sq = reinterpret_cast<const float4*>(S + (size_t)tok * Tc);
  unsigned long long key[8];
#pragma unroll
  for (int r = 0; r < 2; ++r) {
    const float4 v4 = Sq[lane * 2 + r];
    const float vv[4] = {v4.x, v4.y, v4.z, v4.w};
#pragma unroll
    for (int c = 0; c < 4; ++c) {
      const int j = lane * 8 + r * 4 + c;
      const unsigned u = __float_as_uint(vv[c]);
      const unsigned s = (u & 0x80000000u) ? ~u : (u | 0x80000000u);
      key[r * 4 + c] = (j <= i)
          ? (((unsigned long long)s << 32) | (unsigned)(511 - j))
          : 0ull;
    }
  }
  unsigned avail = 0;
  for (int m = 0; m < 16; ++m) {
    unsigned long long bk = 0;
#pragma unroll
    for (int r = 0; r < 8; ++r) bk = (key[r] > bk) ? key[r] : bk;
#pragma unroll
    for (int msk = 1; msk <= 32; msk <<= 1) {
      const unsigned long long ok = __shfl_xor(bk, msk);
      bk = (ok > bk) ? ok : bk;
    }
    const int j = 511 - (int)(unsigned)(bk & 0xFFFFFFFFull);
    const unsigned shi = (unsigned)(bk >> 32);
    if (lane == 0) topidx[(size_t)tok * 16 + m] = j & 511;
    if (shi > 0x007FFFFFu && j != i) avail |= (1u << m);
#pragma unroll
    for (int r = 0; r < 8; ++r) key[r] = (key[r] == bk) ? 0ull : key[r];
  }
  if (lane == 0) availB[tok] = avail;
}

// ---------------------------------------------------------------------------
// Greedy DPP selection, 4 tokens/wave, incremental-Cholesky scoring (R4/R5 —
// bit-identical decision math, passing for 2 rounds).
// ---------------------------------------------------------------------------
__global__ void __launch_bounds__(64, 4) select4_kernel(
    const float* __restrict__ qkv, const int* __restrict__ topidx,
    const unsigned* __restrict__ availB, float* __restrict__ y) {
  const int bid = blockIdx.x;          // 4 tokens per block
  const int bh = bid >> 7;             // 128 blocks per (b,h)
  const int i0 = (bid & 127) << 2;
  const int b = bh / Hc;
  const int h = bh % Hc;
  const int lane = threadIdx.x;
  const int g = lane >> 4;             // token group 0..3
  const int l16 = lane & 15;
  const int i_g = i0 + g;
  const int tok0 = bh * Tc + i0;

  const float* base = qkv + (size_t)b * Tc * QKVN + h * HSc;
  const float* kbase = base + Cc;
  const float* vbase = base + 2 * Cc;

  __shared__ float Kc[4][17][68];      // cands 0..15 + k_i at 16; pad 68
  __shared__ int topidxS[4][16];
  __shared__ int selS[4][8];

  // ---- load precomputed top-16 + avail ----
  topidxS[lane >> 4][lane & 15] =
      topidx[(size_t)(tok0 + (lane >> 4)) * 16 + (lane & 15)];
  unsigned avail = availB[tok0 + g];
  __syncthreads();

  // ---- gather candidate k-rows + k_i into LDS (coalesced) ----
#pragma unroll
  for (int g2 = 0; g2 < 4; ++g2)
    for (int m2 = 0; m2 < 17; ++m2) {
      const int j = (m2 < 16) ? topidxS[g2][m2] : (i0 + g2);
      Kc[g2][m2][lane] = kbase[(size_t)j * QKVN + lane];
    }
  __syncthreads();

  // ---- cnorm, z0, kii (f64 dots from LDS) ----
  const float4* myrow = reinterpret_cast<const float4*>(&Kc[g][l16][0]);
  const float4* irow  = reinterpret_cast<const float4*>(&Kc[g][16][0]);
  double cnorm = 0.0, c0 = 0.0, kii = 0.0;
#pragma unroll
  for (int q = 0; q < 16; ++q) {
    const float4 a4 = myrow[q];
    const float4 i4 = irow[q];
    cnorm += (double)a4.x * a4.x; cnorm += (double)a4.y * a4.y;
    cnorm += (double)a4.z * a4.z; cnorm += (double)a4.w * a4.w;
    c0    += (double)a4.x * i4.x; c0    += (double)a4.y * i4.y;
    c0    += (double)a4.z * i4.z; c0    += (double)a4.w * i4.w;
    kii   += (double)i4.x * i4.x; kii   += (double)i4.y * i4.y;
    kii   += (double)i4.z * i4.z; kii   += (double)i4.w * i4.w;
  }
  double z[8];
#pragma unroll
  for (int t = 0; t < 8; ++t) z[t] = 0.0;
  z[0] = c0 / sqrt(kii);
  double schur = cnorm - z[0] * z[0];
  double detS = kii;
  double cur_s = -log(kii + EPSd);
  int count = 1;
  bool done = false;
  if (l16 == 0) selS[g][0] = i_g;

  // ---- greedy loop, fully unrolled (static z indices) ----
#pragma unroll
  for (int it = 0; it < 7; ++it) {
    if (__ballot(done) != ~0ull) {
      const double D = detS * schur + EPSd;
      const double sval = -log(D) / (double)(it + 2);
      const bool act = (!done) && ((avail >> l16) & 1u);
      const double sorig = act ? sval : -INFINITY;
      // group argmax; NaN acts as max (numpy argmax), ties -> lower m
      double bkey = __builtin_isnan(sorig) ? INFINITY : sorig;
      int bm = l16;
#pragma unroll
      for (int msk = 1; msk <= 8; msk <<= 1) {
        const double ok2 = __shfl_xor(bkey, msk);
        const int om = __shfl_xor(bm, msk);
        const bool t2 = (ok2 > bkey) || (ok2 == bkey && om < bm);
        bkey = t2 ? ok2 : bkey;
        bm = t2 ? om : bm;
      }
      const int srcl = (g << 4) | bm;
      const double best_s = __shfl(sorig, srcl);   // original (maybe NaN)
      const bool X = (avail != 0u) && ((best_s > cur_s) || (it == 0));
      const bool accept = (!done) && X;
      // broadcast z_b, schur_b (outside the divergent if)
      const double schur_b = __shfl(schur, srcl);
      double sum = 0.0;
#pragma unroll
      for (int t = 0; t <= it; ++t) {
        const double zbt = __shfl(z[t], srcl);
        sum += z[t] * zbt;
      }
      if (accept) {
        const float4* brow = reinterpret_cast<const float4*>(&Kc[g][bm][0]);
        double cp = 0.0;
#pragma unroll
        for (int q = 0; q < 16; ++q) {
          const float4 a4 = myrow[q];
          const float4 b4 = brow[q];
          cp += (double)a4.x * b4.x; cp += (double)a4.y * b4.y;
          cp += (double)a4.z * b4.z; cp += (double)a4.w * b4.w;
        }
        const double znew = (cp - sum) / sqrt(schur_b);
        z[it + 1] = znew;
        schur -= znew * znew;
        detS *= schur_b;
        cur_s = best_s;
        avail &= ~(1u << bm);
        ++count;
        if (l16 == 0) selS[g][it + 1] = topidxS[g][bm];
      }
      done = done || (!X);
    }
  }
  __syncthreads();

  // ---- output = mean of selected v rows; y is [B,T,H,HS] ----
#pragma unroll
  for (int g2 = 0; g2 < 4; ++g2) {
    const int cnt = __shfl(count, g2 << 4);
    double acc = 0.0;
#pragma unroll
    for (int a = 0; a < 8; ++a)
      if (a < cnt) acc += (double)vbase[(size_t)selS[g2][a] * QKVN + lane];
    y[(((size_t)b * Tc + (i0 + g2)) * Hc + h) * HSc + lane] =
        (float)(acc / (double)cnt);
  }
}

// ---------------------------------------------------------------------------
extern "C" void kernel_launch(void* const* d_in, const int* in_sizes, int n_in,
                              void* d_out, int out_size, void* d_ws, size_t ws_size,
                              hipStream_t stream) {
  (void)in_sizes; (void)n_in; (void)out_size; (void)ws_size;
  const float* x  = (const float*)d_in[0];
  const float* Wa = (const float*)d_in[1];
  const float* ba = (const float*)d_in[2];
  const float* Wp = (const float*)d_in[3];
  const float* bp = (const float*)d_in[4];
  float* out = (float*)d_out;

  float* qkv = (float*)d_ws;                          // [B*T][2304]  18.9MB
  float* y   = qkv + (size_t)Bc * Tc * QKVN;          // [B*T][768]    6.3MB
  float* S   = y + (size_t)Bc * Tc * Cc;              // [48][512][512] 50.3MB
  int* topidx = (int*)(S + (size_t)Bc * Hc * Tc * Tc);     // [24576][16] 1.6MB
  unsigned* availB = (unsigned*)(topidx + (size_t)Bc * Hc * Tc * 16);  // 98KB

  // 1) qkv = x @ W_attn + b_attn (fp32 tiled, 64x128 tiles -> 576 blocks)
  hipLaunchKernelGGL((gemm_tiled<64, 128, 8, 4>),
                     dim3((Bc * Tc) / 64, QKVN / 128), dim3(256), 0,
                     stream, x, Wa, ba, qkv, QKVN);
  // 2) S = Q K^T per head, lower-triangle tiles only (36 per head)
  hipLaunchKernelGGL(sims_kernel, dim3(36, Bc * Hc), dim3(256), 0,
                     stream, qkv, S);
  // 3) top-16 per token (one wave per token; masks j>i itself)
  hipLaunchKernelGGL(topk_kernel, dim3(Bc * Hc * Tc / 4), dim3(256), 0,
                     stream, S, topidx, availB);
  // 4) greedy DPP, 4 tokens/wave, incremental Cholesky
  hipLaunchKernelGGL(select4_kernel, dim3(Bc * Hc * Tc / 4), dim3(64), 0,
                     stream, qkv, topidx, availB, y);
  // 5) out = y @ W_proj + b_proj (fp32 tiled, 64x64 tiles -> 384 blocks)
  hipLaunchKernelGGL((gemm_tiled<64, 64, 4, 4>),
                     dim3((Bc * Tc) / 64, Cc / 64), dim3(256), 0,
                     stream, y, Wp, bp, out, Cc);
}

// Round 7
// 399.922 us; speedup vs baseline: 2.7153x; 1.0745x over previous
//
#include <hip/hip_runtime.h>
#include <math.h>

// Problem constants (from reference):
constexpr int Bc = 4, Tc = 512, Cc = 768, Hc = 12, HSc = 64;
constexpr int QKVN = 3 * Cc;  // 2304
constexpr double EPSd = 1e-6;

// ---------------------------------------------------------------------------
// Split-K fp32 GEMM partial: P[ks] = X[:, kBeg:kBeg+kps] @ W[kBeg:kBeg+kps, :]
// 128x128 tile, thread = 16x4 accs (64), BK=8. As transposed [k][m] ->
// a-frags are 2-address wave-broadcast b128; b-frags tx*16B -> conflict-free.
// Register prefetch of next stage overlaps global latency with compute.
// M fixed = 2048. Deterministic (fixed split boundaries).
// ---------------------------------------------------------------------------
__global__ void __launch_bounds__(256) gemm_splitk(
    const float* __restrict__ X, const float* __restrict__ W,
    float* __restrict__ P, int N, int kPerSplit) {
  constexpr int BK = 8;
  __shared__ float As[BK][132];
  __shared__ float Bs[BK][132];
  const int tid = threadIdx.x;
  const int tx = tid & 31;          // 32 col groups of TN=4
  const int ty = tid >> 5;          // 8 row groups of TM=16
  const int rb = blockIdx.x * 128;
  const int cb = blockIdx.y * 128;
  const int kBeg = blockIdx.z * kPerSplit;
  const int arow = tid >> 1, ak4 = (tid & 1) * 4;
  const int bkk = tid >> 5, bn4 = (tid & 31) * 4;
  const float* aptr = &X[(size_t)(rb + arow) * Cc + kBeg + ak4];
  const float* bptr = &W[(size_t)(kBeg + bkk) * N + cb + bn4];
  float acc[16][4];
#pragma unroll
  for (int m = 0; m < 16; ++m)
#pragma unroll
    for (int n = 0; n < 4; ++n) acc[m][n] = 0.0f;

  const int nIter = kPerSplit / BK;
  float4 a4 = *(const float4*)aptr;
  float4 b4 = *(const float4*)bptr;
  for (int it = 0; it < nIter; ++it) {
    __syncthreads();  // previous compute done reading LDS
    As[ak4 + 0][arow] = a4.x;
    As[ak4 + 1][arow] = a4.y;
    As[ak4 + 2][arow] = a4.z;
    As[ak4 + 3][arow] = a4.w;
    *(float4*)&Bs[bkk][bn4] = b4;
    __syncthreads();
    if (it + 1 < nIter) {  // prefetch next stage into registers
      aptr += BK;
      bptr += (size_t)BK * N;
      a4 = *(const float4*)aptr;
      b4 = *(const float4*)bptr;
    }
#pragma unroll
    for (int kk = 0; kk < BK; ++kk) {
      float av[16];
#pragma unroll
      for (int m4 = 0; m4 < 4; ++m4) {
        const float4 af = *(const float4*)&As[kk][ty * 16 + m4 * 4];
        av[m4 * 4 + 0] = af.x; av[m4 * 4 + 1] = af.y;
        av[m4 * 4 + 2] = af.z; av[m4 * 4 + 3] = af.w;
      }
      const float4 bf = *(const float4*)&Bs[kk][tx * 4];
      const float bv[4] = {bf.x, bf.y, bf.z, bf.w};
#pragma unroll
      for (int m = 0; m < 16; ++m)
#pragma unroll
        for (int n = 0; n < 4; ++n) acc[m][n] += av[m] * bv[n];
    }
  }
  float* Pp = P + (size_t)blockIdx.z * ((size_t)2048 * N);
#pragma unroll
  for (int m = 0; m < 16; ++m) {
    const float4 o = {acc[m][0], acc[m][1], acc[m][2], acc[m][3]};
    *(float4*)&Pp[(size_t)(rb + ty * 16 + m) * N + cb + tx * 4] = o;
  }
}

// ---------------------------------------------------------------------------
// out = sum_ks P[ks] + bias (fixed order -> deterministic). float4 vectorized.
// ---------------------------------------------------------------------------
__global__ void __launch_bounds__(256) reduce_bias_kernel(
    const float* __restrict__ P, const float* __restrict__ bias,
    float* __restrict__ outp, int MN, int N, int KS) {
  const int idx4 = (blockIdx.x * 256 + threadIdx.x) * 4;
  float4 acc = *(const float4*)&P[idx4];
  for (int ks = 1; ks < KS; ++ks) {
    const float4 p = *(const float4*)&P[(size_t)ks * MN + idx4];
    acc.x += p.x; acc.y += p.y; acc.z += p.z; acc.w += p.w;
  }
  const int col = idx4 % N;
  const float4 b4 = *(const float4*)&bias[col];
  acc.x += b4.x; acc.y += b4.y; acc.z += b4.z; acc.w += b4.w;
  *(float4*)&outp[idx4] = acc;
}

// ---------------------------------------------------------------------------
// S[bh][i][j] = q_i . k_j (fp32). LOWER-TRIANGLE TILES ONLY; j>i masked in
// topk. 64x64x64 tile, 4x4 register tile, operands transposed [d][tok] in LDS.
// ---------------------------------------------------------------------------
__global__ void __launch_bounds__(256) sims_kernel(
    const float* __restrict__ qkv, float* __restrict__ S) {
  const int bh = blockIdx.y;
  const int b = bh / Hc, h = bh % Hc;
  int it = 0;
  {
    const int t = blockIdx.x;
    while ((it + 1) * (it + 2) / 2 <= t) ++it;
  }
  const int jt = blockIdx.x - it * (it + 1) / 2;
  const int tid = threadIdx.x;
  const int tx = tid & 15, ty = tid >> 4;
  __shared__ float Qs[HSc][68];
  __shared__ float Ks[HSc][68];
  const float* base = qkv + (size_t)b * Tc * QKVN + h * HSc;
  {
    const int row = tid >> 2;
    const int d0 = (tid & 3) * 16;
    const float* qrow = base + (size_t)(it * 64 + row) * QKVN;
    const float* krow = base + (size_t)(jt * 64 + row) * QKVN + Cc;
#pragma unroll
    for (int u = 0; u < 4; ++u) {
      const float4 q4 = *(const float4*)&qrow[d0 + u * 4];
      const float4 k4 = *(const float4*)&krow[d0 + u * 4];
      Qs[d0 + u * 4 + 0][row] = q4.x; Qs[d0 + u * 4 + 1][row] = q4.y;
      Qs[d0 + u * 4 + 2][row] = q4.z; Qs[d0 + u * 4 + 3][row] = q4.w;
      Ks[d0 + u * 4 + 0][row] = k4.x; Ks[d0 + u * 4 + 1][row] = k4.y;
      Ks[d0 + u * 4 + 2][row] = k4.z; Ks[d0 + u * 4 + 3][row] = k4.w;
    }
  }
  __syncthreads();
  float acc[4][4];
#pragma unroll
  for (int m = 0; m < 4; ++m)
#pragma unroll
    for (int n = 0; n < 4; ++n) acc[m][n] = 0.0f;
#pragma unroll 4
  for (int d = 0; d < HSc; ++d) {
    const float4 a4 = *(const float4*)&Qs[d][ty * 4];
    const float4 b4 = *(const float4*)&Ks[d][tx * 4];
    const float a[4] = {a4.x, a4.y, a4.z, a4.w};
    const float bv[4] = {b4.x, b4.y, b4.z, b4.w};
#pragma unroll
    for (int m = 0; m < 4; ++m)
#pragma unroll
      for (int n = 0; n < 4; ++n) acc[m][n] += a[m] * bv[n];
  }
  float* Shead = S + (size_t)bh * Tc * Tc;
#pragma unroll
  for (int m = 0; m < 4; ++m) {
    const int i = it * 64 + ty * 4 + m;
    float4 o4 = {acc[m][0], acc[m][1], acc[m][2], acc[m][3]};
    *(float4*)&Shead[(size_t)i * Tc + jt * 64 + tx * 4] = o4;
  }
}

// ---------------------------------------------------------------------------
// Top-16 per token row, one full wave per token. key=(sortable(f32)<<32)|
// (511-j) -> exact jax.lax.top_k semantics; j>i masked here (key=0).
// ---------------------------------------------------------------------------
__global__ void __launch_bounds__(256) topk_kernel(
    const float* __restrict__ S, int* __restrict__ topidx,
    unsigned* __restrict__ availB) {
  const int tid = threadIdx.x;
  const int wv = tid >> 6, lane = tid & 63;
  const int tok = blockIdx.x * 4 + wv;  // bh*512 + i
  const int i = tok & (Tc - 1);
  const float4* Sq = reinterpret_cast<const float4*>(S + (size_t)tok * Tc);
  unsigned long long key[8];
#pragma unroll
  for (int r = 0; r < 2; ++r) {
    const float4 v4 = Sq[lane * 2 + r];
    const float vv[4] = {v4.x, v4.y, v4.z, v4.w};
#pragma unroll
    for (int c = 0; c < 4; ++c) {
      const int j = lane * 8 + r * 4 + c;
      const unsigned u = __float_as_uint(vv[c]);
      const unsigned s = (u & 0x80000000u) ? ~u : (u | 0x80000000u);
      key[r * 4 + c] = (j <= i)
          ? (((unsigned long long)s << 32) | (unsigned)(511 - j))
          : 0ull;
    }
  }
  unsigned avail = 0;
  for (int m = 0; m < 16; ++m) {
    unsigned long long bk = 0;
#pragma unroll
    for (int r = 0; r < 8; ++r) bk = (key[r] > bk) ? key[r] : bk;
#pragma unroll
    for (int msk = 1; msk <= 32; msk <<= 1) {
      const unsigned long long ok = __shfl_xor(bk, msk);
      bk = (ok > bk) ? ok : bk;
    }
    const int j = 511 - (int)(unsigned)(bk & 0xFFFFFFFFull);
    const unsigned shi = (unsigned)(bk >> 32);
    if (lane == 0) topidx[(size_t)tok * 16 + m] = j & 511;
    if (shi > 0x007FFFFFu && j != i) avail |= (1u << m);
#pragma unroll
    for (int r = 0; r < 8; ++r) key[r] = (key[r] == bk) ? 0ull : key[r];
  }
  if (lane == 0) availB[tok] = avail;
}

// ---------------------------------------------------------------------------
// Greedy DPP selection, 4 tokens/wave, incremental-Cholesky scoring (R4-R6 —
// bit-identical decision math, passing for 3 rounds).
// ---------------------------------------------------------------------------
__global__ void __launch_bounds__(64, 4) select4_kernel(
    const float* __restrict__ qkv, const int* __restrict__ topidx,
    const unsigned* __restrict__ availB, float* __restrict__ y) {
  const int bid = blockIdx.x;          // 4 tokens per block
  const int bh = bid >> 7;             // 128 blocks per (b,h)
  const int i0 = (bid & 127) << 2;
  const int b = bh / Hc;
  const int h = bh % Hc;
  const int lane = threadIdx.x;
  const int g = lane >> 4;             // token group 0..3
  const int l16 = lane & 15;
  const int i_g = i0 + g;
  const int tok0 = bh * Tc + i0;

  const float* base = qkv + (size_t)b * Tc * QKVN + h * HSc;
  const float* kbase = base + Cc;
  const float* vbase = base + 2 * Cc;

  __shared__ float Kc[4][17][68];      // cands 0..15 + k_i at 16; pad 68
  __shared__ int topidxS[4][16];
  __shared__ int selS[4][8];

  // ---- load precomputed top-16 + avail ----
  topidxS[lane >> 4][lane & 15] =
      topidx[(size_t)(tok0 + (lane >> 4)) * 16 + (lane & 15)];
  unsigned avail = availB[tok0 + g];
  __syncthreads();

  // ---- gather candidate k-rows + k_i into LDS (coalesced) ----
#pragma unroll
  for (int g2 = 0; g2 < 4; ++g2)
    for (int m2 = 0; m2 < 17; ++m2) {
      const int j = (m2 < 16) ? topidxS[g2][m2] : (i0 + g2);
      Kc[g2][m2][lane] = kbase[(size_t)j * QKVN + lane];
    }
  __syncthreads();

  // ---- cnorm, z0, kii (f64 dots from LDS) ----
  const float4* myrow = reinterpret_cast<const float4*>(&Kc[g][l16][0]);
  const float4* irow  = reinterpret_cast<const float4*>(&Kc[g][16][0]);
  double cnorm = 0.0, c0 = 0.0, kii = 0.0;
#pragma unroll
  for (int q = 0; q < 16; ++q) {
    const float4 a4 = myrow[q];
    const float4 i4 = irow[q];
    cnorm += (double)a4.x * a4.x; cnorm += (double)a4.y * a4.y;
    cnorm += (double)a4.z * a4.z; cnorm += (double)a4.w * a4.w;
    c0    += (double)a4.x * i4.x; c0    += (double)a4.y * i4.y;
    c0    += (double)a4.z * i4.z; c0    += (double)a4.w * i4.w;
    kii   += (double)i4.x * i4.x; kii   += (double)i4.y * i4.y;
    kii   += (double)i4.z * i4.z; kii   += (double)i4.w * i4.w;
  }
  double z[8];
#pragma unroll
  for (int t = 0; t < 8; ++t) z[t] = 0.0;
  z[0] = c0 / sqrt(kii);
  double schur = cnorm - z[0] * z[0];
  double detS = kii;
  double cur_s = -log(kii + EPSd);
  int count = 1;
  bool done = false;
  if (l16 == 0) selS[g][0] = i_g;

  // ---- greedy loop, fully unrolled (static z indices) ----
#pragma unroll
  for (int it = 0; it < 7; ++it) {
    if (__ballot(done) != ~0ull) {
      const double D = detS * schur + EPSd;
      const double sval = -log(D) / (double)(it + 2);
      const bool act = (!done) && ((avail >> l16) & 1u);
      const double sorig = act ? sval : -INFINITY;
      // group argmax; NaN acts as max (numpy argmax), ties -> lower m
      double bkey = __builtin_isnan(sorig) ? INFINITY : sorig;
      int bm = l16;
#pragma unroll
      for (int msk = 1; msk <= 8; msk <<= 1) {
        const double ok2 = __shfl_xor(bkey, msk);
        const int om = __shfl_xor(bm, msk);
        const bool t2 = (ok2 > bkey) || (ok2 == bkey && om < bm);
        bkey = t2 ? ok2 : bkey;
        bm = t2 ? om : bm;
      }
      const int srcl = (g << 4) | bm;
      const double best_s = __shfl(sorig, srcl);   // original (maybe NaN)
      const bool X = (avail != 0u) && ((best_s > cur_s) || (it == 0));
      const bool accept = (!done) && X;
      // broadcast z_b, schur_b (outside the divergent if)
      const double schur_b = __shfl(schur, srcl);
      double sum = 0.0;
#pragma unroll
      for (int t = 0; t <= it; ++t) {
        const double zbt = __shfl(z[t], srcl);
        sum += z[t] * zbt;
      }
      if (accept) {
        const float4* brow = reinterpret_cast<const float4*>(&Kc[g][bm][0]);
        double cp = 0.0;
#pragma unroll
        for (int q = 0; q < 16; ++q) {
          const float4 a4 = myrow[q];
          const float4 b4 = brow[q];
          cp += (double)a4.x * b4.x; cp += (double)a4.y * b4.y;
          cp += (double)a4.z * b4.z; cp += (double)a4.w * b4.w;
        }
        const double znew = (cp - sum) / sqrt(schur_b);
        z[it + 1] = znew;
        schur -= znew * znew;
        detS *= schur_b;
        cur_s = best_s;
        avail &= ~(1u << bm);
        ++count;
        if (l16 == 0) selS[g][it + 1] = topidxS[g][bm];
      }
      done = done || (!X);
    }
  }
  __syncthreads();

  // ---- output = mean of selected v rows; y is [B,T,H,HS] ----
#pragma unroll
  for (int g2 = 0; g2 < 4; ++g2) {
    const int cnt = __shfl(count, g2 << 4);
    double acc = 0.0;
#pragma unroll
    for (int a = 0; a < 8; ++a)
      if (a < cnt) acc += (double)vbase[(size_t)selS[g2][a] * QKVN + lane];
    y[(((size_t)b * Tc + (i0 + g2)) * Hc + h) * HSc + lane] =
        (float)(acc / (double)cnt);
  }
}

// ---------------------------------------------------------------------------
extern "C" void kernel_launch(void* const* d_in, const int* in_sizes, int n_in,
                              void* d_out, int out_size, void* d_ws, size_t ws_size,
                              hipStream_t stream) {
  (void)in_sizes; (void)n_in; (void)out_size; (void)ws_size;
  const float* x  = (const float*)d_in[0];
  const float* Wa = (const float*)d_in[1];
  const float* ba = (const float*)d_in[2];
  const float* Wp = (const float*)d_in[3];
  const float* bp = (const float*)d_in[4];
  float* out = (float*)d_out;

  // Workspace layout (77.2 MB total — same footprint as the passing R6):
  float* qkv = (float*)d_ws;                            // 18.87 MB
  float* y   = qkv + (size_t)Bc * Tc * QKVN;            //  6.29 MB
  int* topidx = (int*)(y + (size_t)Bc * Tc * Cc);       //  1.57 MB
  unsigned* availB = (unsigned*)(topidx + (size_t)Bc * Hc * Tc * 16);  // 98 KB
  // Region B (aliased, 50.33 MB): S, then qkv split-K partials (37.75 MB),
  // then proj split-K partials (37.75 MB). Stream order guarantees no overlap
  // in lifetime: Pqkv dead after reduce -> S written by sims; S dead after
  // topk -> Pproj written by proj gemm.
  float* regionB = (float*)(availB + (size_t)Bc * Hc * Tc);
  float* S = regionB;
  float* Pqkv = regionB;
  float* Pproj = regionB;

  const int MNqkv = Bc * Tc * QKVN;  // 4,718,592
  const int MNproj = Bc * Tc * Cc;   // 1,572,864

  // 1) qkv partials (KS=2, k-slice 384) + reduce with bias
  hipLaunchKernelGGL(gemm_splitk, dim3(16, QKVN / 128, 2), dim3(256), 0,
                     stream, x, Wa, Pqkv, QKVN, 384);
  hipLaunchKernelGGL(reduce_bias_kernel, dim3(MNqkv / 1024), dim3(256), 0,
                     stream, Pqkv, ba, qkv, MNqkv, QKVN, 2);
  // 2) S = Q K^T per head, lower-triangle tiles only
  hipLaunchKernelGGL(sims_kernel, dim3(36, Bc * Hc), dim3(256), 0,
                     stream, qkv, S);
  // 3) top-16 per token
  hipLaunchKernelGGL(topk_kernel, dim3(Bc * Hc * Tc / 4), dim3(256), 0,
                     stream, S, topidx, availB);
  // 4) greedy DPP, 4 tokens/wave, incremental Cholesky
  hipLaunchKernelGGL(select4_kernel, dim3(Bc * Hc * Tc / 4), dim3(64), 0,
                     stream, qkv, topidx, availB, y);
  // 5) proj partials (KS=6, k-slice 128) + reduce with bias
  hipLaunchKernelGGL(gemm_splitk, dim3(16, Cc / 128, 6), dim3(256), 0,
                     stream, y, Wp, Pproj, Cc, 128);
  hipLaunchKernelGGL(reduce_bias_kernel, dim3(MNproj / 1024), dim3(256), 0,
                     stream, Pproj, bp, out, MNproj, Cc, 6);
}

// Round 8
// 395.649 us; speedup vs baseline: 2.7446x; 1.0108x over previous
//
#include <hip/hip_runtime.h>
#include <math.h>

// Problem constants (from reference):
constexpr int Bc = 4, Tc = 512, Cc = 768, Hc = 12, HSc = 64;
constexpr int QKVN = 3 * Cc;  // 2304
constexpr double EPSd = 1e-6;

// ---------------------------------------------------------------------------
// Split-K fp32 GEMM partial, 128x128 tile, thread tile 8x8 (LDS-balanced:
// 64 B LDS per 64 FMA = 2 FLOP/B -> at the 128 B/cyc LDS ceiling, FMA can run
// at peak; R7's 16x4 tile was capped at 53%). BK=16. Both LDS tiles stored as
// [k][chunk16][8 floats + 1 pad] so 32B fragments are <=2-way bank aliased
// (free) per quarter-wave; B-fragment reads are quarter-uniform broadcasts.
// Register prefetch of next stage. Deterministic (fixed split boundaries).
// ---------------------------------------------------------------------------
__global__ void __launch_bounds__(256, 2) gemm_splitk(
    const float* __restrict__ X, const float* __restrict__ W,
    float* __restrict__ P, int N, int kPerSplit) {
  constexpr int BK = 16;
  __shared__ float As[BK][16][9];  // [k][rowChunk][row&7]
  __shared__ float Bs[BK][16][9];  // [k][colChunk][col&7]
  const int tid = threadIdx.x;
  const int tx = tid >> 4;   // col group 0..15 (TN=8)
  const int ty = tid & 15;   // row group 0..15 (TM=8)
  const int rb = blockIdx.x * 128;
  const int cb = blockIdx.y * 128;
  const int kBeg = blockIdx.z * kPerSplit;
  // staging assignments
  const int arow = tid >> 1;          // 0..127
  const int ak8 = (tid & 1) * 8;      // 0 or 8
  const int bkk = tid >> 4;           // 0..15
  const int bc8 = tid & 15;           // col chunk 0..15
  const float* aptr = &X[(size_t)(rb + arow) * Cc + kBeg + ak8];
  const float* bptr = &W[(size_t)(kBeg + bkk) * N + cb + bc8 * 8];
  float acc[8][8];
#pragma unroll
  for (int m = 0; m < 8; ++m)
#pragma unroll
    for (int n = 0; n < 8; ++n) acc[m][n] = 0.0f;

  const int nIter = kPerSplit / BK;
  float4 a0 = *(const float4*)aptr;
  float4 a1 = *(const float4*)(aptr + 4);
  float4 b0 = *(const float4*)bptr;
  float4 b1 = *(const float4*)(bptr + 4);
  for (int it = 0; it < nIter; ++it) {
    __syncthreads();  // previous compute done reading LDS
    {
      const int rc = arow >> 3, rr = arow & 7;
      As[ak8 + 0][rc][rr] = a0.x; As[ak8 + 1][rc][rr] = a0.y;
      As[ak8 + 2][rc][rr] = a0.z; As[ak8 + 3][rc][rr] = a0.w;
      As[ak8 + 4][rc][rr] = a1.x; As[ak8 + 5][rc][rr] = a1.y;
      As[ak8 + 6][rc][rr] = a1.z; As[ak8 + 7][rc][rr] = a1.w;
      *(float4*)&Bs[bkk][bc8][0] = b0;
      *(float4*)&Bs[bkk][bc8][4] = b1;
    }
    __syncthreads();
    if (it + 1 < nIter) {  // prefetch next stage into registers
      aptr += BK;
      bptr += (size_t)BK * N;
      a0 = *(const float4*)aptr;
      a1 = *(const float4*)(aptr + 4);
      b0 = *(const float4*)bptr;
      b1 = *(const float4*)(bptr + 4);
    }
#pragma unroll
    for (int kk = 0; kk < BK; ++kk) {
      const float4 af0 = *(const float4*)&As[kk][ty][0];
      const float4 af1 = *(const float4*)&As[kk][ty][4];
      const float4 bf0 = *(const float4*)&Bs[kk][tx][0];
      const float4 bf1 = *(const float4*)&Bs[kk][tx][4];
      const float av[8] = {af0.x, af0.y, af0.z, af0.w,
                           af1.x, af1.y, af1.z, af1.w};
      const float bv[8] = {bf0.x, bf0.y, bf0.z, bf0.w,
                           bf1.x, bf1.y, bf1.z, bf1.w};
#pragma unroll
      for (int m = 0; m < 8; ++m)
#pragma unroll
        for (int n = 0; n < 8; ++n) acc[m][n] += av[m] * bv[n];
    }
  }
  float* Pp = P + (size_t)blockIdx.z * ((size_t)2048 * N);
#pragma unroll
  for (int m = 0; m < 8; ++m) {
    const size_t orow = (size_t)(rb + ty * 8 + m) * N + cb + tx * 8;
    const float4 o0 = {acc[m][0], acc[m][1], acc[m][2], acc[m][3]};
    const float4 o1 = {acc[m][4], acc[m][5], acc[m][6], acc[m][7]};
    *(float4*)&Pp[orow] = o0;
    *(float4*)&Pp[orow + 4] = o1;
  }
}

// ---------------------------------------------------------------------------
// out = sum_ks P[ks] + bias (fixed order -> deterministic). float4 vectorized.
// ---------------------------------------------------------------------------
__global__ void __launch_bounds__(256) reduce_bias_kernel(
    const float* __restrict__ P, const float* __restrict__ bias,
    float* __restrict__ outp, int MN, int N, int KS) {
  const int idx4 = (blockIdx.x * 256 + threadIdx.x) * 4;
  float4 acc = *(const float4*)&P[idx4];
  for (int ks = 1; ks < KS; ++ks) {
    const float4 p = *(const float4*)&P[(size_t)ks * MN + idx4];
    acc.x += p.x; acc.y += p.y; acc.z += p.z; acc.w += p.w;
  }
  const int col = idx4 % N;
  const float4 b4 = *(const float4*)&bias[col];
  acc.x += b4.x; acc.y += b4.y; acc.z += b4.z; acc.w += b4.w;
  *(float4*)&outp[idx4] = acc;
}

// ---------------------------------------------------------------------------
// S[bh][i][j] = q_i . k_j (fp32). LOWER-TRIANGLE TILES ONLY; j>i masked in
// topk. 64x64x64 tile, 4x4 register tile, operands transposed [d][tok] in LDS.
// ---------------------------------------------------------------------------
__global__ void __launch_bounds__(256) sims_kernel(
    const float* __restrict__ qkv, float* __restrict__ S) {
  const int bh = blockIdx.y;
  const int b = bh / Hc, h = bh % Hc;
  int it = 0;
  {
    const int t = blockIdx.x;
    while ((it + 1) * (it + 2) / 2 <= t) ++it;
  }
  const int jt = blockIdx.x - it * (it + 1) / 2;
  const int tid = threadIdx.x;
  const int tx = tid & 15, ty = tid >> 4;
  __shared__ float Qs[HSc][68];
  __shared__ float Ks[HSc][68];
  const float* base = qkv + (size_t)b * Tc * QKVN + h * HSc;
  {
    const int row = tid >> 2;
    const int d0 = (tid & 3) * 16;
    const float* qrow = base + (size_t)(it * 64 + row) * QKVN;
    const float* krow = base + (size_t)(jt * 64 + row) * QKVN + Cc;
#pragma unroll
    for (int u = 0; u < 4; ++u) {
      const float4 q4 = *(const float4*)&qrow[d0 + u * 4];
      const float4 k4 = *(const float4*)&krow[d0 + u * 4];
      Qs[d0 + u * 4 + 0][row] = q4.x; Qs[d0 + u * 4 + 1][row] = q4.y;
      Qs[d0 + u * 4 + 2][row] = q4.z; Qs[d0 + u * 4 + 3][row] = q4.w;
      Ks[d0 + u * 4 + 0][row] = k4.x; Ks[d0 + u * 4 + 1][row] = k4.y;
      Ks[d0 + u * 4 + 2][row] = k4.z; Ks[d0 + u * 4 + 3][row] = k4.w;
    }
  }
  __syncthreads();
  float acc[4][4];
#pragma unroll
  for (int m = 0; m < 4; ++m)
#pragma unroll
    for (int n = 0; n < 4; ++n) acc[m][n] = 0.0f;
#pragma unroll 4
  for (int d = 0; d < HSc; ++d) {
    const float4 a4 = *(const float4*)&Qs[d][ty * 4];
    const float4 b4 = *(const float4*)&Ks[d][tx * 4];
    const float a[4] = {a4.x, a4.y, a4.z, a4.w};
    const float bv[4] = {b4.x, b4.y, b4.z, b4.w};
#pragma unroll
    for (int m = 0; m < 4; ++m)
#pragma unroll
      for (int n = 0; n < 4; ++n) acc[m][n] += a[m] * bv[n];
  }
  float* Shead = S + (size_t)bh * Tc * Tc;
#pragma unroll
  for (int m = 0; m < 4; ++m) {
    const int i = it * 64 + ty * 4 + m;
    float4 o4 = {acc[m][0], acc[m][1], acc[m][2], acc[m][3]};
    *(float4*)&Shead[(size_t)i * Tc + jt * 64 + tx * 4] = o4;
  }
}

// ---------------------------------------------------------------------------
// Top-16 per token row, one full wave per token. key=(sortable(f32)<<32)|
// (511-j) -> exact jax.lax.top_k semantics; j>i masked here (key=0).
// ---------------------------------------------------------------------------
__global__ void __launch_bounds__(256) topk_kernel(
    const float* __restrict__ S, int* __restrict__ topidx,
    unsigned* __restrict__ availB) {
  const int tid = threadIdx.x;
  const int wv = tid >> 6, lane = tid & 63;
  const int tok = blockIdx.x * 4 + wv;  // bh*512 + i
  const int i = tok & (Tc - 1);
  const float4* Sq = reinterpret_cast<const float4*>(S + (size_t)tok * Tc);
  unsigned long long key[8];
#pragma unroll
  for (int r = 0; r < 2; ++r) {
    const float4 v4 = Sq[lane * 2 + r];
    const float vv[4] = {v4.x, v4.y, v4.z, v4.w};
#pragma unroll
    for (int c = 0; c < 4; ++c) {
      const int j = lane * 8 + r * 4 + c;
      const unsigned u = __float_as_uint(vv[c]);
      const unsigned s = (u & 0x80000000u) ? ~u : (u | 0x80000000u);
      key[r * 4 + c] = (j <= i)
          ? (((unsigned long long)s << 32) | (unsigned)(511 - j))
          : 0ull;
    }
  }
  unsigned avail = 0;
  for (int m = 0; m < 16; ++m) {
    unsigned long long bk = 0;
#pragma unroll
    for (int r = 0; r < 8; ++r) bk = (key[r] > bk) ? key[r] : bk;
#pragma unroll
    for (int msk = 1; msk <= 32; msk <<= 1) {
      const unsigned long long ok = __shfl_xor(bk, msk);
      bk = (ok > bk) ? ok : bk;
    }
    const int j = 511 - (int)(unsigned)(bk & 0xFFFFFFFFull);
    const unsigned shi = (unsigned)(bk >> 32);
    if (lane == 0) topidx[(size_t)tok * 16 + m] = j & 511;
    if (shi > 0x007FFFFFu && j != i) avail |= (1u << m);
#pragma unroll
    for (int r = 0; r < 8; ++r) key[r] = (key[r] == bk) ? 0ull : key[r];
  }
  if (lane == 0) availB[tok] = avail;
}

// ---------------------------------------------------------------------------
// Greedy DPP selection, ONE token per wave, 4 lanes per candidate, all
// candidate data in REGISTERS (zero big-LDS -> ~2.5x occupancy vs R7's
// LDS-resident version). Incremental-Cholesky scoring as R4-R7:
//   det(G_{S u c}) = detS * schur_c;  z-recursion in f64.
// Gram dots now fp32 (reference's own gram is fp32 E@E.T -> same ~1e-7
// perturbation class already proven flip-free for 4 rounds).
// ---------------------------------------------------------------------------
__global__ void __launch_bounds__(256, 4) select_kernel(
    const float* __restrict__ qkv, const int* __restrict__ topidx,
    const unsigned* __restrict__ availB, float* __restrict__ y) {
  const int tid = threadIdx.x;
  const int wv = tid >> 6, lane = tid & 63;
  const int tok = blockIdx.x * 4 + wv;  // bh*512 + i
  const int bh = tok >> 9;
  const int i = tok & (Tc - 1);
  const int b = bh / Hc;
  const int h = bh % Hc;
  const int m = lane >> 2;   // candidate 0..15
  const int q = lane & 3;    // quarter 0..3 (16 dims each)

  const float* base = qkv + (size_t)b * Tc * QKVN + h * HSc;
  const float* kbase = base + Cc;
  const float* vbase = base + 2 * Cc;

  __shared__ int selS[4][8];

  const int tidx = topidx[(size_t)tok * 16 + m];  // cluster-uniform
  unsigned avail = availB[tok];                   // wave-uniform

  // gather my candidate's quarter + k_i's quarter into registers
  float kreg[16], kireg[16];
  {
    const float* kc = kbase + (size_t)tidx * QKVN + q * 16;
    const float* ki = kbase + (size_t)i * QKVN + q * 16;
#pragma unroll
    for (int u = 0; u < 4; ++u) {
      const float4 c4 = *(const float4*)&kc[u * 4];
      const float4 i4 = *(const float4*)&ki[u * 4];
      kreg[u * 4 + 0] = c4.x; kreg[u * 4 + 1] = c4.y;
      kreg[u * 4 + 2] = c4.z; kreg[u * 4 + 3] = c4.w;
      kireg[u * 4 + 0] = i4.x; kireg[u * 4 + 1] = i4.y;
      kireg[u * 4 + 2] = i4.z; kireg[u * 4 + 3] = i4.w;
    }
  }
  // fp32 partial dots + cluster reduce (shfl_xor 1,2)
  float cnorm_f = 0.0f, c0_f = 0.0f, kii_f = 0.0f;
#pragma unroll
  for (int e = 0; e < 16; ++e) {
    cnorm_f += kreg[e] * kreg[e];
    c0_f += kreg[e] * kireg[e];
    kii_f += kireg[e] * kireg[e];
  }
  cnorm_f += __shfl_xor(cnorm_f, 1); cnorm_f += __shfl_xor(cnorm_f, 2);
  c0_f += __shfl_xor(c0_f, 1);       c0_f += __shfl_xor(c0_f, 2);
  kii_f += __shfl_xor(kii_f, 1);     kii_f += __shfl_xor(kii_f, 2);

  const double kii = (double)kii_f;
  double z[8];
#pragma unroll
  for (int t = 0; t < 8; ++t) z[t] = 0.0;
  z[0] = (double)c0_f / sqrt(kii);
  double schur = (double)cnorm_f - z[0] * z[0];
  double detS = kii;
  double cur_s = -log(kii + EPSd);
  int count = 1;
  if (lane == 0) selS[wv][0] = i;

  // greedy loop: all accept/compare decisions wave-uniform
#pragma unroll
  for (int it = 0; it < 7; ++it) {
    const double D = detS * schur + EPSd;
    const double sval = -log(D) / (double)(it + 2);
    const bool act = (avail >> m) & 1u;
    const double sorig = act ? sval : -INFINITY;
    // wave argmax over 16 candidates (4-lane clusters carry equal keys);
    // NaN acts as max (numpy argmax), ties -> lower m
    double bkey = __builtin_isnan(sorig) ? INFINITY : sorig;
    int bm = m;
#pragma unroll
    for (int msk = 1; msk <= 32; msk <<= 1) {
      const double ok2 = __shfl_xor(bkey, msk);
      const int om = __shfl_xor(bm, msk);
      const bool t2 = (ok2 > bkey) || (ok2 == bkey && om < bm);
      bkey = t2 ? ok2 : bkey;
      bm = t2 ? om : bm;
    }
    const double best_s = __shfl(sorig, bm * 4);  // original (maybe NaN)
    const bool X = (avail != 0u) && ((best_s > cur_s) || (it == 0));
    if (!X) break;  // wave-uniform: first reject -> done forever
    // cp = k_c . k_best: element shfls from the owner cluster's q-th lane
    float cp_f = 0.0f;
#pragma unroll
    for (int e = 0; e < 16; ++e) {
      const float kb = __shfl(kreg[e], bm * 4 + q);
      cp_f += kreg[e] * kb;
    }
    cp_f += __shfl_xor(cp_f, 1); cp_f += __shfl_xor(cp_f, 2);
    // z-recursion in f64 (z of candidate bm is cluster-replicated)
    const double schur_b = __shfl(schur, bm * 4);
    double sum = 0.0;
#pragma unroll
    for (int t = 0; t <= it; ++t) {
      const double zbt = __shfl(z[t], bm * 4);
      sum += z[t] * zbt;
    }
    const double znew = ((double)cp_f - sum) / sqrt(schur_b);
    z[it + 1] = znew;
    schur -= znew * znew;
    detS *= schur_b;
    cur_s = best_s;
    avail &= ~(1u << bm);
    ++count;
    const int selIdx = __shfl(tidx, bm * 4);
    if (lane == 0) selS[wv][it + 1] = selIdx;
  }

  // output = mean of selected v rows; y is [B,T,H,HS]
  double acc = 0.0;
#pragma unroll
  for (int a = 0; a < 8; ++a)
    if (a < count) acc += (double)vbase[(size_t)selS[wv][a] * QKVN + lane];
  y[(((size_t)b * Tc + i) * Hc + h) * HSc + lane] =
      (float)(acc / (double)count);
}

// ---------------------------------------------------------------------------
extern "C" void kernel_launch(void* const* d_in, const int* in_sizes, int n_in,
                              void* d_out, int out_size, void* d_ws, size_t ws_size,
                              hipStream_t stream) {
  (void)in_sizes; (void)n_in; (void)out_size; (void)ws_size;
  const float* x  = (const float*)d_in[0];
  const float* Wa = (const float*)d_in[1];
  const float* ba = (const float*)d_in[2];
  const float* Wp = (const float*)d_in[3];
  const float* bp = (const float*)d_in[4];
  float* out = (float*)d_out;

  // Workspace layout (77.2 MB total — same footprint as the passing R6/R7):
  float* qkv = (float*)d_ws;                            // 18.87 MB
  float* y   = qkv + (size_t)Bc * Tc * QKVN;            //  6.29 MB
  int* topidx = (int*)(y + (size_t)Bc * Tc * Cc);       //  1.57 MB
  unsigned* availB = (unsigned*)(topidx + (size_t)Bc * Hc * Tc * 16);  // 98 KB
  // Region B (aliased, 50.33 MB): Pqkv (37.75) -> S (50.33) -> Pproj (37.75);
  // stream order guarantees disjoint lifetimes.
  float* regionB = (float*)(availB + (size_t)Bc * Hc * Tc);
  float* S = regionB;
  float* Pqkv = regionB;
  float* Pproj = regionB;

  const int MNqkv = Bc * Tc * QKVN;  // 4,718,592
  const int MNproj = Bc * Tc * Cc;   // 1,572,864

  // 1) qkv partials (KS=2, k-slice 384) + reduce with bias
  hipLaunchKernelGGL(gemm_splitk, dim3(16, QKVN / 128, 2), dim3(256), 0,
                     stream, x, Wa, Pqkv, QKVN, 384);
  hipLaunchKernelGGL(reduce_bias_kernel, dim3(MNqkv / 1024), dim3(256), 0,
                     stream, Pqkv, ba, qkv, MNqkv, QKVN, 2);
  // 2) S = Q K^T per head, lower-triangle tiles only
  hipLaunchKernelGGL(sims_kernel, dim3(36, Bc * Hc), dim3(256), 0,
                     stream, qkv, S);
  // 3) top-16 per token
  hipLaunchKernelGGL(topk_kernel, dim3(Bc * Hc * Tc / 4), dim3(256), 0,
                     stream, S, topidx, availB);
  // 4) greedy DPP, 1 token/wave, register-resident candidates
  hipLaunchKernelGGL(select_kernel, dim3(Bc * Hc * Tc / 4), dim3(256), 0,
                     stream, qkv, topidx, availB, y);
  // 5) proj partials (KS=6, k-slice 128) + reduce with bias
  hipLaunchKernelGGL(gemm_splitk, dim3(16, Cc / 128, 6), dim3(256), 0,
                     stream, y, Wp, Pproj, Cc, 128);
  hipLaunchKernelGGL(reduce_bias_kernel, dim3(MNproj / 1024), dim3(256), 0,
                     stream, Pproj, bp, out, MNproj, Cc, 6);
}

// Round 9
// 352.311 us; speedup vs baseline: 3.0822x; 1.1230x over previous
//
#include <hip/hip_runtime.h>
#include <math.h>

// Problem constants (from reference):
constexpr int Bc = 4, Tc = 512, Cc = 768, Hc = 12, HSc = 64;
constexpr int QKVN = 3 * Cc;  // 2304
constexpr double EPSd = 1e-6;

// ---------------------------------------------------------------------------
// fp32 GEMM, 64x64 tile, 4x4 thread tile, BK=32. Many light blocks (qkv:
// 1152 = 4.5/CU) instead of R7/R8's 576 heavy ones -> tail shrinks 1.33->1.19
// and barriers hide behind ~16 resident waves/CU. Per kk: 2 ds_read_b128
// (24 cyc LDS pipe) vs 16 wave-FMA (32 cyc VALU) -> VALU-bound with overlap.
// As/Bs stride 68 floats: frag reads <=2-way aliased (free); A-scatter writes
// 4-way (~73 cyc per 1024-cyc stage, negligible). WRITE_PARTIAL=false adds
// bias and writes C directly (no split-K, no reduce); true writes partials.
// ---------------------------------------------------------------------------
template <bool WRITE_PARTIAL>
__global__ void __launch_bounds__(256, 4) gemm64(
    const float* __restrict__ X, const float* __restrict__ W,
    const float* __restrict__ bias, float* __restrict__ outp,
    int N, int kPerSplit) {
  constexpr int BK = 32;
  __shared__ float As[BK][68];  // [k][row], transposed
  __shared__ float Bs[BK][68];  // [k][col]
  const int tid = threadIdx.x;
  const int tx = tid & 15;   // col group (TN=4)
  const int ty = tid >> 4;   // row group (TM=4)
  const int rb = blockIdx.x * 64;
  const int cb = blockIdx.y * 64;
  const int kBeg = blockIdx.z * kPerSplit;
  // staging assignments
  const int arow = tid >> 2;        // 0..63
  const int ak8 = (tid & 3) * 8;    // 0,8,16,24
  const int bkk = tid >> 3;         // 0..31
  const int bc8 = (tid & 7) * 8;    // 0..56
  const float* aptr = &X[(size_t)(rb + arow) * Cc + kBeg + ak8];
  const float* bptr = &W[(size_t)(kBeg + bkk) * N + cb + bc8];
  float acc[4][4];
#pragma unroll
  for (int m = 0; m < 4; ++m)
#pragma unroll
    for (int n = 0; n < 4; ++n) acc[m][n] = 0.0f;

  const int nIter = kPerSplit / BK;
  float4 a0 = *(const float4*)aptr;
  float4 a1 = *(const float4*)(aptr + 4);
  float4 b0 = *(const float4*)bptr;
  float4 b1 = *(const float4*)(bptr + 4);
  for (int it = 0; it < nIter; ++it) {
    __syncthreads();  // previous compute done reading LDS
    As[ak8 + 0][arow] = a0.x; As[ak8 + 1][arow] = a0.y;
    As[ak8 + 2][arow] = a0.z; As[ak8 + 3][arow] = a0.w;
    As[ak8 + 4][arow] = a1.x; As[ak8 + 5][arow] = a1.y;
    As[ak8 + 6][arow] = a1.z; As[ak8 + 7][arow] = a1.w;
    *(float4*)&Bs[bkk][bc8] = b0;
    *(float4*)&Bs[bkk][bc8 + 4] = b1;
    __syncthreads();
    if (it + 1 < nIter) {  // prefetch next stage into registers
      aptr += BK;
      bptr += (size_t)BK * N;
      a0 = *(const float4*)aptr;
      a1 = *(const float4*)(aptr + 4);
      b0 = *(const float4*)bptr;
      b1 = *(const float4*)(bptr + 4);
    }
#pragma unroll
    for (int kk = 0; kk < BK; ++kk) {
      const float4 af = *(const float4*)&As[kk][ty * 4];
      const float4 bf = *(const float4*)&Bs[kk][tx * 4];
      const float av[4] = {af.x, af.y, af.z, af.w};
      const float bv[4] = {bf.x, bf.y, bf.z, bf.w};
#pragma unroll
      for (int m = 0; m < 4; ++m)
#pragma unroll
        for (int n = 0; n < 4; ++n) acc[m][n] += av[m] * bv[n];
    }
  }
  if (WRITE_PARTIAL) {
    float* Pp = outp + (size_t)blockIdx.z * ((size_t)2048 * N);
#pragma unroll
    for (int m = 0; m < 4; ++m) {
      const float4 o = {acc[m][0], acc[m][1], acc[m][2], acc[m][3]};
      *(float4*)&Pp[(size_t)(rb + ty * 4 + m) * N + cb + tx * 4] = o;
    }
  } else {
    const float4 b4 = *(const float4*)&bias[cb + tx * 4];
#pragma unroll
    for (int m = 0; m < 4; ++m) {
      const float4 o = {acc[m][0] + b4.x, acc[m][1] + b4.y,
                        acc[m][2] + b4.z, acc[m][3] + b4.w};
      *(float4*)&outp[(size_t)(rb + ty * 4 + m) * N + cb + tx * 4] = o;
    }
  }
}

// ---------------------------------------------------------------------------
// out = sum_ks P[ks] + bias (fixed order -> deterministic). float4 vectorized.
// ---------------------------------------------------------------------------
__global__ void __launch_bounds__(256) reduce_bias_kernel(
    const float* __restrict__ P, const float* __restrict__ bias,
    float* __restrict__ outp, int MN, int N, int KS) {
  const int idx4 = (blockIdx.x * 256 + threadIdx.x) * 4;
  float4 acc = *(const float4*)&P[idx4];
  for (int ks = 1; ks < KS; ++ks) {
    const float4 p = *(const float4*)&P[(size_t)ks * MN + idx4];
    acc.x += p.x; acc.y += p.y; acc.z += p.z; acc.w += p.w;
  }
  const int col = idx4 % N;
  const float4 b4 = *(const float4*)&bias[col];
  acc.x += b4.x; acc.y += b4.y; acc.z += b4.z; acc.w += b4.w;
  *(float4*)&outp[idx4] = acc;
}

// ---------------------------------------------------------------------------
// S[bh][i][j] = q_i . k_j (fp32). LOWER-TRIANGLE TILES ONLY; j>i masked in
// topk. 64x64x64 tile, 4x4 register tile, operands transposed [d][tok] in LDS.
// ---------------------------------------------------------------------------
__global__ void __launch_bounds__(256) sims_kernel(
    const float* __restrict__ qkv, float* __restrict__ S) {
  const int bh = blockIdx.y;
  const int b = bh / Hc, h = bh % Hc;
  int it = 0;
  {
    const int t = blockIdx.x;
    while ((it + 1) * (it + 2) / 2 <= t) ++it;
  }
  const int jt = blockIdx.x - it * (it + 1) / 2;
  const int tid = threadIdx.x;
  const int tx = tid & 15, ty = tid >> 4;
  __shared__ float Qs[HSc][68];
  __shared__ float Ks[HSc][68];
  const float* base = qkv + (size_t)b * Tc * QKVN + h * HSc;
  {
    const int row = tid >> 2;
    const int d0 = (tid & 3) * 16;
    const float* qrow = base + (size_t)(it * 64 + row) * QKVN;
    const float* krow = base + (size_t)(jt * 64 + row) * QKVN + Cc;
#pragma unroll
    for (int u = 0; u < 4; ++u) {
      const float4 q4 = *(const float4*)&qrow[d0 + u * 4];
      const float4 k4 = *(const float4*)&krow[d0 + u * 4];
      Qs[d0 + u * 4 + 0][row] = q4.x; Qs[d0 + u * 4 + 1][row] = q4.y;
      Qs[d0 + u * 4 + 2][row] = q4.z; Qs[d0 + u * 4 + 3][row] = q4.w;
      Ks[d0 + u * 4 + 0][row] = k4.x; Ks[d0 + u * 4 + 1][row] = k4.y;
      Ks[d0 + u * 4 + 2][row] = k4.z; Ks[d0 + u * 4 + 3][row] = k4.w;
    }
  }
  __syncthreads();
  float acc[4][4];
#pragma unroll
  for (int m = 0; m < 4; ++m)
#pragma unroll
    for (int n = 0; n < 4; ++n) acc[m][n] = 0.0f;
#pragma unroll 4
  for (int d = 0; d < HSc; ++d) {
    const float4 a4 = *(const float4*)&Qs[d][ty * 4];
    const float4 b4 = *(const float4*)&Ks[d][tx * 4];
    const float a[4] = {a4.x, a4.y, a4.z, a4.w};
    const float bv[4] = {b4.x, b4.y, b4.z, b4.w};
#pragma unroll
    for (int m = 0; m < 4; ++m)
#pragma unroll
      for (int n = 0; n < 4; ++n) acc[m][n] += a[m] * bv[n];
  }
  float* Shead = S + (size_t)bh * Tc * Tc;
#pragma unroll
  for (int m = 0; m < 4; ++m) {
    const int i = it * 64 + ty * 4 + m;
    float4 o4 = {acc[m][0], acc[m][1], acc[m][2], acc[m][3]};
    *(float4*)&Shead[(size_t)i * Tc + jt * 64 + tx * 4] = o4;
  }
}

// ---------------------------------------------------------------------------
// Top-16 per token row, one full wave per token. key=(sortable(f32)<<32)|
// (511-j) -> exact jax.lax.top_k semantics; j>i masked here (key=0).
// ---------------------------------------------------------------------------
__global__ void __launch_bounds__(256) topk_kernel(
    const float* __restrict__ S, int* __restrict__ topidx,
    unsigned* __restrict__ availB) {
  const int tid = threadIdx.x;
  const int wv = tid >> 6, lane = tid & 63;
  const int tok = blockIdx.x * 4 + wv;  // bh*512 + i
  const int i = tok & (Tc - 1);
  const float4* Sq = reinterpret_cast<const float4*>(S + (size_t)tok * Tc);
  unsigned long long key[8];
#pragma unroll
  for (int r = 0; r < 2; ++r) {
    const float4 v4 = Sq[lane * 2 + r];
    const float vv[4] = {v4.x, v4.y, v4.z, v4.w};
#pragma unroll
    for (int c = 0; c < 4; ++c) {
      const int j = lane * 8 + r * 4 + c;
      const unsigned u = __float_as_uint(vv[c]);
      const unsigned s = (u & 0x80000000u) ? ~u : (u | 0x80000000u);
      key[r * 4 + c] = (j <= i)
          ? (((unsigned long long)s << 32) | (unsigned)(511 - j))
          : 0ull;
    }
  }
  unsigned avail = 0;
  for (int m = 0; m < 16; ++m) {
    unsigned long long bk = 0;
#pragma unroll
    for (int r = 0; r < 8; ++r) bk = (key[r] > bk) ? key[r] : bk;
#pragma unroll
    for (int msk = 1; msk <= 32; msk <<= 1) {
      const unsigned long long ok = __shfl_xor(bk, msk);
      bk = (ok > bk) ? ok : bk;
    }
    const int j = 511 - (int)(unsigned)(bk & 0xFFFFFFFFull);
    const unsigned shi = (unsigned)(bk >> 32);
    if (lane == 0) topidx[(size_t)tok * 16 + m] = j & 511;
    if (shi > 0x007FFFFFu && j != i) avail |= (1u << m);
#pragma unroll
    for (int r = 0; r < 8; ++r) key[r] = (key[r] == bk) ? 0ull : key[r];
  }
  if (lane == 0) availB[tok] = avail;
}

// ---------------------------------------------------------------------------
// Greedy DPP selection, ONE token per wave, 4 lanes per candidate, all
// candidate data in REGISTERS. Incremental-Cholesky scoring (R4-R8, proven).
// ---------------------------------------------------------------------------
__global__ void __launch_bounds__(256, 4) select_kernel(
    const float* __restrict__ qkv, const int* __restrict__ topidx,
    const unsigned* __restrict__ availB, float* __restrict__ y) {
  const int tid = threadIdx.x;
  const int wv = tid >> 6, lane = tid & 63;
  const int tok = blockIdx.x * 4 + wv;  // bh*512 + i
  const int bh = tok >> 9;
  const int i = tok & (Tc - 1);
  const int b = bh / Hc;
  const int h = bh % Hc;
  const int m = lane >> 2;   // candidate 0..15
  const int q = lane & 3;    // quarter 0..3 (16 dims each)

  const float* base = qkv + (size_t)b * Tc * QKVN + h * HSc;
  const float* kbase = base + Cc;
  const float* vbase = base + 2 * Cc;

  __shared__ int selS[4][8];

  const int tidx = topidx[(size_t)tok * 16 + m];  // cluster-uniform
  unsigned avail = availB[tok];                   // wave-uniform

  // gather my candidate's quarter + k_i's quarter into registers
  float kreg[16], kireg[16];
  {
    const float* kc = kbase + (size_t)tidx * QKVN + q * 16;
    const float* ki = kbase + (size_t)i * QKVN + q * 16;
#pragma unroll
    for (int u = 0; u < 4; ++u) {
      const float4 c4 = *(const float4*)&kc[u * 4];
      const float4 i4 = *(const float4*)&ki[u * 4];
      kreg[u * 4 + 0] = c4.x; kreg[u * 4 + 1] = c4.y;
      kreg[u * 4 + 2] = c4.z; kreg[u * 4 + 3] = c4.w;
      kireg[u * 4 + 0] = i4.x; kireg[u * 4 + 1] = i4.y;
      kireg[u * 4 + 2] = i4.z; kireg[u * 4 + 3] = i4.w;
    }
  }
  // fp32 partial dots + cluster reduce (shfl_xor 1,2)
  float cnorm_f = 0.0f, c0_f = 0.0f, kii_f = 0.0f;
#pragma unroll
  for (int e = 0; e < 16; ++e) {
    cnorm_f += kreg[e] * kreg[e];
    c0_f += kreg[e] * kireg[e];
    kii_f += kireg[e] * kireg[e];
  }
  cnorm_f += __shfl_xor(cnorm_f, 1); cnorm_f += __shfl_xor(cnorm_f, 2);
  c0_f += __shfl_xor(c0_f, 1);       c0_f += __shfl_xor(c0_f, 2);
  kii_f += __shfl_xor(kii_f, 1);     kii_f += __shfl_xor(kii_f, 2);

  const double kii = (double)kii_f;
  double z[8];
#pragma unroll
  for (int t = 0; t < 8; ++t) z[t] = 0.0;
  z[0] = (double)c0_f / sqrt(kii);
  double schur = (double)cnorm_f - z[0] * z[0];
  double detS = kii;
  double cur_s = -log(kii + EPSd);
  int count = 1;
  if (lane == 0) selS[wv][0] = i;

  // greedy loop: all accept/compare decisions wave-uniform
#pragma unroll
  for (int it = 0; it < 7; ++it) {
    const double D = detS * schur + EPSd;
    const double sval = -log(D) / (double)(it + 2);
    const bool act = (avail >> m) & 1u;
    const double sorig = act ? sval : -INFINITY;
    // wave argmax over 16 candidates (4-lane clusters carry equal keys);
    // NaN acts as max (numpy argmax), ties -> lower m
    double bkey = __builtin_isnan(sorig) ? INFINITY : sorig;
    int bm = m;
#pragma unroll
    for (int msk = 1; msk <= 32; msk <<= 1) {
      const double ok2 = __shfl_xor(bkey, msk);
      const int om = __shfl_xor(bm, msk);
      const bool t2 = (ok2 > bkey) || (ok2 == bkey && om < bm);
      bkey = t2 ? ok2 : bkey;
      bm = t2 ? om : bm;
    }
    const double best_s = __shfl(sorig, bm * 4);  // original (maybe NaN)
    const bool X = (avail != 0u) && ((best_s > cur_s) || (it == 0));
    if (!X) break;  // wave-uniform: first reject -> done forever
    // cp = k_c . k_best: element shfls from the owner cluster's q-th lane
    float cp_f = 0.0f;
#pragma unroll
    for (int e = 0; e < 16; ++e) {
      const float kb = __shfl(kreg[e], bm * 4 + q);
      cp_f += kreg[e] * kb;
    }
    cp_f += __shfl_xor(cp_f, 1); cp_f += __shfl_xor(cp_f, 2);
    // z-recursion in f64 (z of candidate bm is cluster-replicated)
    const double schur_b = __shfl(schur, bm * 4);
    double sum = 0.0;
#pragma unroll
    for (int t = 0; t <= it; ++t) {
      const double zbt = __shfl(z[t], bm * 4);
      sum += z[t] * zbt;
    }
    const double znew = ((double)cp_f - sum) / sqrt(schur_b);
    z[it + 1] = znew;
    schur -= znew * znew;
    detS *= schur_b;
    cur_s = best_s;
    avail &= ~(1u << bm);
    ++count;
    const int selIdx = __shfl(tidx, bm * 4);
    if (lane == 0) selS[wv][it + 1] = selIdx;
  }

  // output = mean of selected v rows; y is [B,T,H,HS]
  double acc = 0.0;
#pragma unroll
  for (int a = 0; a < 8; ++a)
    if (a < count) acc += (double)vbase[(size_t)selS[wv][a] * QKVN + lane];
  y[(((size_t)b * Tc + i) * Hc + h) * HSc + lane] =
      (float)(acc / (double)count);
}

// ---------------------------------------------------------------------------
extern "C" void kernel_launch(void* const* d_in, const int* in_sizes, int n_in,
                              void* d_out, int out_size, void* d_ws, size_t ws_size,
                              hipStream_t stream) {
  (void)in_sizes; (void)n_in; (void)out_size; (void)ws_size;
  const float* x  = (const float*)d_in[0];
  const float* Wa = (const float*)d_in[1];
  const float* ba = (const float*)d_in[2];
  const float* Wp = (const float*)d_in[3];
  const float* bp = (const float*)d_in[4];
  float* out = (float*)d_out;

  // Workspace layout (77.2 MB total — same footprint as R5-R8):
  float* qkv = (float*)d_ws;                            // 18.87 MB
  float* y   = qkv + (size_t)Bc * Tc * QKVN;            //  6.29 MB
  int* topidx = (int*)(y + (size_t)Bc * Tc * Cc);       //  1.57 MB
  unsigned* availB = (unsigned*)(topidx + (size_t)Bc * Hc * Tc * 16);  // 98 KB
  // Region B (aliased, 50.33 MB): S (50.33) -> Pproj (18.87);
  // stream order guarantees disjoint lifetimes (S dead after topk).
  float* regionB = (float*)(availB + (size_t)Bc * Hc * Tc);
  float* S = regionB;
  float* Pproj = regionB;

  const int MNproj = Bc * Tc * Cc;   // 1,572,864

  // 1) qkv = x @ W_attn + b_attn  (no split-K: 32x36 = 1152 blocks, k=768)
  hipLaunchKernelGGL((gemm64<false>), dim3(32, QKVN / 64, 1), dim3(256), 0,
                     stream, x, Wa, ba, qkv, QKVN, Cc);
  // 2) S = Q K^T per head, lower-triangle tiles only
  hipLaunchKernelGGL(sims_kernel, dim3(36, Bc * Hc), dim3(256), 0,
                     stream, qkv, S);
  // 3) top-16 per token
  hipLaunchKernelGGL(topk_kernel, dim3(Bc * Hc * Tc / 4), dim3(256), 0,
                     stream, S, topidx, availB);
  // 4) greedy DPP, 1 token/wave, register-resident candidates
  hipLaunchKernelGGL(select_kernel, dim3(Bc * Hc * Tc / 4), dim3(256), 0,
                     stream, qkv, topidx, availB, y);
  // 5) proj partials (KS=3, k-slice 256; 32x12x3 = 1152 blocks) + reduce
  hipLaunchKernelGGL((gemm64<true>), dim3(32, Cc / 64, 3), dim3(256), 0,
                     stream, y, Wp, nullptr, Pproj, Cc, 256);
  hipLaunchKernelGGL(reduce_bias_kernel, dim3(MNproj / 1024), dim3(256), 0,
                     stream, Pproj, bp, out, MNproj, Cc, 3);
}